// Round 2
// baseline (175.238 us; speedup 1.0000x reference)
//
#include <hip/hip_runtime.h>
#include <hip/hip_bf16.h>

typedef __attribute__((ext_vector_type(8))) short short8;
typedef __attribute__((ext_vector_type(4))) float f32x4;

#define B_ROWS 8192
#define HDIM 512
#define NDIM 1024
#define MDIM 128

__device__ __forceinline__ float softplusf(float z) {
  return fmaxf(z, 0.f) + log1pf(__expf(-fabsf(z)));
}
__device__ __forceinline__ unsigned short f2bfu(float f) {
  __hip_bfloat16 h = __float2bfloat16(f);   // round-to-nearest-even
  return *reinterpret_cast<unsigned short*>(&h);
}
__device__ __forceinline__ short8 pack8(float4 a, float4 b) {
  short8 r;
  r[0] = (short)f2bfu(a.x); r[1] = (short)f2bfu(a.y);
  r[2] = (short)f2bfu(a.z); r[3] = (short)f2bfu(a.w);
  r[4] = (short)f2bfu(b.x); r[5] = (short)f2bfu(b.y);
  r[6] = (short)f2bfu(b.z); r[7] = (short)f2bfu(b.w);
  return r;
}

// ---------------------------------------------------------------------------
// GEMM: C[m][n] = sum_k A[m][k] * W[n][k]  (+bias[n]) ; fp32 in, bf16 MFMA,
// fp32 out. Tile 64x64, 4 waves (2x2), K-step 32, mfma_f32_16x16x32_bf16.
// ---------------------------------------------------------------------------
__global__ __launch_bounds__(256) void gemm_bt(
    const float* __restrict__ A, const float* __restrict__ W,
    const float* __restrict__ bias, float* __restrict__ C,
    int ncols, int K)
{
  __shared__ __align__(16) short sA[64][40];
  __shared__ __align__(16) short sW[64][40];

  const int tid = threadIdx.x;
  const int bm = blockIdx.y, bn = blockIdx.x;
  const int lrow = tid >> 2;           // 0..63
  const int lcol = (tid & 3) << 3;     // 0,8,16,24
  const int wid = tid >> 6, lane = tid & 63;
  const int wr = wid >> 1, wc = wid & 1;
  const int fr = lane & 15, kg = (lane >> 4) << 3;

  f32x4 acc[2][2] = {};

  const size_t arow = (size_t)(bm * 64 + lrow) * K + lcol;
  const size_t wrow = (size_t)(bn * 64 + lrow) * K + lcol;

  for (int k0 = 0; k0 < K; k0 += 32) {
    const float4 a0 = *(const float4*)(A + arow + k0);
    const float4 a1 = *(const float4*)(A + arow + k0 + 4);
    const float4 w0 = *(const float4*)(W + wrow + k0);
    const float4 w1 = *(const float4*)(W + wrow + k0 + 4);
    *(short8*)(&sA[lrow][lcol]) = pack8(a0, a1);
    *(short8*)(&sW[lrow][lcol]) = pack8(w0, w1);
    __syncthreads();

    short8 af[2], bf[2];
#pragma unroll
    for (int i = 0; i < 2; i++) af[i] = *(const short8*)(&sA[wr * 32 + i * 16 + fr][kg]);
#pragma unroll
    for (int n = 0; n < 2; n++) bf[n] = *(const short8*)(&sW[wc * 32 + n * 16 + fr][kg]);

#pragma unroll
    for (int i = 0; i < 2; i++)
#pragma unroll
      for (int n = 0; n < 2; n++)
        acc[i][n] = __builtin_amdgcn_mfma_f32_16x16x32_bf16(af[i], bf[n], acc[i][n], 0, 0, 0);
    __syncthreads();
  }

#pragma unroll
  for (int i = 0; i < 2; i++)
#pragma unroll
    for (int n = 0; n < 2; n++) {
      const int gr = bm * 64 + wr * 32 + i * 16 + ((lane >> 4) << 2);
      const int gc = bn * 64 + wc * 32 + n * 16 + fr;
      const float bv = bias ? bias[gc] : 0.f;
#pragma unroll
      for (int r = 0; r < 4; r++)
        C[(size_t)(gr + r) * ncols + gc] = acc[i][n][r] + bv;
    }
}

// ---------------------------------------------------------------------------
// Normalize memory rows -> mn (fp32) and build memT (fp32, [M][N]).
// ---------------------------------------------------------------------------
__global__ __launch_bounds__(128) void prep_mem(const float* __restrict__ mem,
    float* __restrict__ mn, float* __restrict__ memT)
{
  const int n = blockIdx.x, t = threadIdx.x;
  const int lane = t & 63, wid = t >> 6;
  const float v = mem[n * MDIM + t];
  float ss = v * v;
#pragma unroll
  for (int o = 32; o; o >>= 1) ss += __shfl_xor(ss, o);
  __shared__ float sred[2];
  if (lane == 0) sred[wid] = ss;
  __syncthreads();
  const float inv = 1.f / fmaxf(sqrtf(sred[0] + sred[1]), 1e-8f);
  mn[n * MDIM + t] = v * inv;
  memT[(size_t)t * NDIM + n] = v;
}

// ---------------------------------------------------------------------------
// Normalize k rows in place (kraw -> k_hat).
// ---------------------------------------------------------------------------
__global__ __launch_bounds__(128) void knorm(float* __restrict__ kraw)
{
  const int b = blockIdx.x, t = threadIdx.x;
  const int lane = t & 63, wid = t >> 6;
  const float v = kraw[(size_t)b * MDIM + t];
  float ss = v * v;
#pragma unroll
  for (int o = 32; o; o >>= 1) ss += __shfl_xor(ss, o);
  __shared__ float sred[2];
  if (lane == 0) sred[wid] = ss;
  __syncthreads();
  const float inv = 1.f / fmaxf(sqrtf(sred[0] + sred[1]), 1e-8f);
  kraw[(size_t)b * MDIM + t] = v * inv;
}

// ---------------------------------------------------------------------------
// beta / g / gamma: one wave per batch row, three 512-length dots.
// ---------------------------------------------------------------------------
__global__ __launch_bounds__(256) void scalars_k(const float* __restrict__ x,
    const float* __restrict__ Wb, const float* __restrict__ bb,
    const float* __restrict__ Wg, const float* __restrict__ bg,
    const float* __restrict__ Wgam, const float* __restrict__ bgam,
    float* __restrict__ bgg)
{
  const int wid = threadIdx.x >> 6, lane = threadIdx.x & 63;
  const int b = blockIdx.x * 4 + wid;
  const size_t xo = (size_t)b * HDIM + lane * 8;
  const float4 x0 = *(const float4*)(x + xo);
  const float4 x1 = *(const float4*)(x + xo + 4);
  const float4 b0 = *(const float4*)(Wb + lane * 8);
  const float4 b1 = *(const float4*)(Wb + lane * 8 + 4);
  const float4 g0 = *(const float4*)(Wg + lane * 8);
  const float4 g1 = *(const float4*)(Wg + lane * 8 + 4);
  const float4 m0 = *(const float4*)(Wgam + lane * 8);
  const float4 m1 = *(const float4*)(Wgam + lane * 8 + 4);
  float zb = x0.x*b0.x + x0.y*b0.y + x0.z*b0.z + x0.w*b0.w
           + x1.x*b1.x + x1.y*b1.y + x1.z*b1.z + x1.w*b1.w;
  float zg = x0.x*g0.x + x0.y*g0.y + x0.z*g0.z + x0.w*g0.w
           + x1.x*g1.x + x1.y*g1.y + x1.z*g1.z + x1.w*g1.w;
  float zm = x0.x*m0.x + x0.y*m0.y + x0.z*m0.z + x0.w*m0.w
           + x1.x*m1.x + x1.y*m1.y + x1.z*m1.z + x1.w*m1.w;
#pragma unroll
  for (int o = 32; o; o >>= 1) {
    zb += __shfl_xor(zb, o); zg += __shfl_xor(zg, o); zm += __shfl_xor(zm, o);
  }
  if (lane == 0) {
    zb += bb[0]; zg += bg[0]; zm += bgam[0];
    bgg[b * 4 + 0] = softplusf(zb);
    bgg[b * 4 + 1] = 1.f / (1.f + __expf(-zg));
    bgg[b * 4 + 2] = 1.f + softplusf(zm);
  }
}

// ---------------------------------------------------------------------------
// Row pass: softmax(s), softmax(beta*cos), gate, FFT circular conv,
// sharpen, normalize.  One 256-thread block per batch row.
// ---------------------------------------------------------------------------
__device__ __forceinline__ float bred_max(float v, float* sred, int lane, int wid) {
#pragma unroll
  for (int o = 32; o; o >>= 1) v = fmaxf(v, __shfl_xor(v, o));
  __syncthreads();
  if (lane == 0) sred[wid] = v;
  __syncthreads();
  return fmaxf(fmaxf(sred[0], sred[1]), fmaxf(sred[2], sred[3]));
}
__device__ __forceinline__ float bred_sum(float v, float* sred, int lane, int wid) {
#pragma unroll
  for (int o = 32; o; o >>= 1) v += __shfl_xor(v, o);
  __syncthreads();
  if (lane == 0) sred[wid] = v;
  __syncthreads();
  return sred[0] + sred[1] + sred[2] + sred[3];
}

// Stockham radix-2 DIF complex FFT, 1024 points, forward (e^{-2pi i nk/N}).
// 10 stages; result ends in x.
__device__ __forceinline__ void fft1024(float2* x, float2* y, const float2* tw, int tid)
{
  float2* src = x;
  float2* dst = y;
  int ns = 1024, s = 1, ls = 0;
  while (ns > 1) {
    const int m = ns >> 1;
    const int tws = 1024 / ns;
#pragma unroll
    for (int i = 0; i < 2; i++) {
      const int t = tid + i * 256;        // 0..511 butterflies
      const int p = t >> ls;
      const int q = t & (s - 1);
      const float2 a = src[q + s * p];
      const float2 b = src[q + s * (p + m)];
      const float2 w = tw[p * tws];
      const float dr = a.x - b.x, di = a.y - b.y;
      dst[q + 2 * s * p]     = make_float2(a.x + b.x, a.y + b.y);
      dst[q + 2 * s * p + s] = make_float2(dr * w.x - di * w.y, dr * w.y + di * w.x);
    }
    __syncthreads();
    float2* tmp = src; src = dst; dst = tmp;
    ns >>= 1; s <<= 1; ls++;
  }
}

__global__ __launch_bounds__(256) void rowpass(
    const float* __restrict__ slog, const float* __restrict__ cosb,
    const float* __restrict__ bgg, const float* __restrict__ prev,
    float* __restrict__ wout)
{
  __shared__ float2 bufA[1024];
  __shared__ float2 bufB[1024];
  __shared__ float2 tw[512];
  __shared__ float sred[4];
  const int b = blockIdx.x, tid = threadIdx.x;
  const int lane = tid & 63, wid = tid >> 6;

  for (int i = tid; i < 512; i += 256) {
    const float ang = -6.283185307179586f * (float)i * (1.0f / 1024.0f);
    float sn, cs; __sincosf(ang, &sn, &cs);
    tw[i] = make_float2(cs, sn);
  }

  const float beta = bgg[b * 4 + 0], g = bgg[b * 4 + 1], gamma = bgg[b * 4 + 2];

  float sv[4], cv[4];
#pragma unroll
  for (int i = 0; i < 4; i++) {
    sv[i] = slog[(size_t)b * NDIM + tid + i * 256];
    cv[i] = beta * cosb[(size_t)b * NDIM + tid + i * 256];
  }
  // softmax over s logits
  float m1 = bred_max(fmaxf(fmaxf(sv[0], sv[1]), fmaxf(sv[2], sv[3])), sred, lane, wid);
  float e1 = 0.f;
#pragma unroll
  for (int i = 0; i < 4; i++) { sv[i] = __expf(sv[i] - m1); e1 += sv[i]; }
  const float r1 = 1.f / bred_sum(e1, sred, lane, wid);
  // softmax over beta*cos
  float m2 = bred_max(fmaxf(fmaxf(cv[0], cv[1]), fmaxf(cv[2], cv[3])), sred, lane, wid);
  float e2 = 0.f;
#pragma unroll
  for (int i = 0; i < 4; i++) { cv[i] = __expf(cv[i] - m2); e2 += cv[i]; }
  const float r2 = 1.f / bred_sum(e2, sred, lane, wid);

  // gate + pack z = w_g + i*s
#pragma unroll
  for (int i = 0; i < 4; i++) {
    const int idx = tid + i * 256;
    const float wc = cv[i] * r2;
    const float pv = prev[(size_t)b * NDIM + idx];
    const float wg = g * wc + (1.f - g) * pv;
    bufA[idx] = make_float2(wg, sv[i] * r1);
  }
  __syncthreads();

  fft1024(bufA, bufB, tw, tid);       // Z in bufA

  // spectral split, multiply, conjugate (prep for ifft-via-forward)
#pragma unroll
  for (int i = 0; i < 4; i++) {
    const int k = tid + i * 256;
    const float2 Zk = bufA[k];
    const float2 Zr = bufA[(1024 - k) & 1023];
    const float2 Wc = make_float2(0.5f * (Zk.x + Zr.x), 0.5f * (Zk.y - Zr.y));
    const float2 Sc = make_float2(0.5f * (Zk.y + Zr.y), 0.5f * (Zr.x - Zk.x));
    const float2 P = make_float2(Wc.x * Sc.x - Wc.y * Sc.y, Wc.x * Sc.y + Wc.y * Sc.x);
    bufB[k] = make_float2(P.x, -P.y);
  }
  __syncthreads();

  fft1024(bufB, bufA, tw, tid);       // conj(FFT(conj(P))) -> result in bufB

  // w_t = Re/1024, clamp, sharpen, normalize
  float wt[4]; float esum = 0.f;
#pragma unroll
  for (int i = 0; i < 4; i++) {
    float v = bufB[tid + i * 256].x * (1.f / 1024.f);
    v = fmaxf(v, 0.f);
    const float p = (v > 0.f) ? __expf(gamma * __logf(v)) : 0.f;
    wt[i] = p; esum += p;
  }
  const float rn = 1.f / (bred_sum(esum, sred, lane, wid) + 1e-16f);
#pragma unroll
  for (int i = 0; i < 4; i++)
    wout[(size_t)b * NDIM + tid + i * 256] = wt[i] * rn;
}

// ---------------------------------------------------------------------------
extern "C" void kernel_launch(void* const* d_in, const int* in_sizes, int n_in,
                              void* d_out, int out_size, void* d_ws, size_t ws_size,
                              hipStream_t stream)
{
  const float* x    = (const float*)d_in[0];
  const float* prev = (const float*)d_in[1];
  const float* mem  = (const float*)d_in[2];
  const float* Wk   = (const float*)d_in[3];
  const float* bk   = (const float*)d_in[4];
  const float* Wb   = (const float*)d_in[5];
  const float* bb   = (const float*)d_in[6];
  const float* Wg   = (const float*)d_in[7];
  const float* bg   = (const float*)d_in[8];
  const float* Ws   = (const float*)d_in[9];
  const float* bs   = (const float*)d_in[10];
  const float* Wgam = (const float*)d_in[11];
  const float* bgam = (const float*)d_in[12];

  char* ws = (char*)d_ws;
  float* mn   = (float*)(ws + 0);          // 1024*128*4 = 512 KB
  float* memT = (float*)(ws + 524288);     // 128*1024*4 = 512 KB
  float* kraw = (float*)(ws + 1048576);    // 8192*128*4 = 4 MB
  float* slog = (float*)(ws + 5242880);    // 8192*1024*4 = 32 MB
  float* cosb = (float*)(ws + 38797312);   // 32 MB
  float* bgg  = (float*)(ws + 72351744);   // 8192*4*4 = 128 KB  (total ~69.2 MB)

  float* readout = (float*)d_out;                          // [8192][128]
  float* wout = readout + (size_t)B_ROWS * MDIM;           // [8192][1024]

  prep_mem<<<NDIM, MDIM, 0, stream>>>(mem, mn, memT);
  gemm_bt<<<dim3(MDIM / 64, B_ROWS / 64), 256, 0, stream>>>(x, Wk, bk, kraw, MDIM, HDIM);
  gemm_bt<<<dim3(NDIM / 64, B_ROWS / 64), 256, 0, stream>>>(x, Ws, bs, slog, NDIM, HDIM);
  scalars_k<<<B_ROWS / 4, 256, 0, stream>>>(x, Wb, bb, Wg, bg, Wgam, bgam, bgg);
  knorm<<<B_ROWS, MDIM, 0, stream>>>(kraw);
  gemm_bt<<<dim3(NDIM / 64, B_ROWS / 64), 256, 0, stream>>>(kraw, mn, nullptr, cosb, NDIM, MDIM);
  rowpass<<<B_ROWS, 256, 0, stream>>>(slog, cosb, bgg, prev, wout);
  gemm_bt<<<dim3(MDIM / 64, B_ROWS / 64), 256, 0, stream>>>(wout, memT, nullptr, readout, MDIM, NDIM);
}

// Round 3
// 157.426 us; speedup vs baseline: 1.1131x; 1.1131x over previous
//
#include <hip/hip_runtime.h>
#include <hip/hip_bf16.h>

typedef __attribute__((ext_vector_type(8))) short short8;
typedef __attribute__((ext_vector_type(4))) float f32x4;

#define B_ROWS 8192
#define HDIM 512
#define NDIM 1024
#define MDIM 128

__device__ __forceinline__ float softplusf(float z) {
  return fmaxf(z, 0.f) + log1pf(__expf(-fabsf(z)));
}
__device__ __forceinline__ unsigned short f2bfu(float f) {
  __hip_bfloat16 h = __float2bfloat16(f);   // round-to-nearest-even
  return *reinterpret_cast<unsigned short*>(&h);
}
__device__ __forceinline__ short8 pack8(float4 a, float4 b) {
  short8 r;
  r[0] = (short)f2bfu(a.x); r[1] = (short)f2bfu(a.y);
  r[2] = (short)f2bfu(a.z); r[3] = (short)f2bfu(a.w);
  r[4] = (short)f2bfu(b.x); r[5] = (short)f2bfu(b.y);
  r[6] = (short)f2bfu(b.z); r[7] = (short)f2bfu(b.w);
  return r;
}

// ---------------------------------------------------------------------------
// GEMM: C[m][n] = sum_k A[m][k] * W[n][k]  (+bias[n]); bf16 MFMA, fp32 out.
// Inputs fp32 (packed to bf16 in staging) or native bf16, per template arg.
// Tile 64x64, 4 waves (2x2), K-step 32, mfma_f32_16x16x32_bf16.
// ---------------------------------------------------------------------------
template<bool AF32, bool WF32>
__global__ __launch_bounds__(256) void gemm_bt(
    const void* __restrict__ Av, const void* __restrict__ Wv,
    const float* __restrict__ bias, float* __restrict__ C,
    int ncols, int K)
{
  __shared__ __align__(16) short sA[64][40];
  __shared__ __align__(16) short sW[64][40];

  const int tid = threadIdx.x;
  const int bm = blockIdx.y, bn = blockIdx.x;
  const int lrow = tid >> 2;           // 0..63
  const int lcol = (tid & 3) << 3;     // 0,8,16,24
  const int wid = tid >> 6, lane = tid & 63;
  const int wr = wid >> 1, wc = wid & 1;
  const int fr = lane & 15, kg = (lane >> 4) << 3;

  f32x4 acc[2][2] = {};

  const size_t arow = (size_t)(bm * 64 + lrow) * K + lcol;
  const size_t wrow = (size_t)(bn * 64 + lrow) * K + lcol;

  for (int k0 = 0; k0 < K; k0 += 32) {
    if constexpr (AF32) {
      const float* A = (const float*)Av;
      const float4 a0 = *(const float4*)(A + arow + k0);
      const float4 a1 = *(const float4*)(A + arow + k0 + 4);
      *(short8*)(&sA[lrow][lcol]) = pack8(a0, a1);
    } else {
      const short* A = (const short*)Av;
      *(short8*)(&sA[lrow][lcol]) = *(const short8*)(A + arow + k0);
    }
    if constexpr (WF32) {
      const float* W = (const float*)Wv;
      const float4 w0 = *(const float4*)(W + wrow + k0);
      const float4 w1 = *(const float4*)(W + wrow + k0 + 4);
      *(short8*)(&sW[lrow][lcol]) = pack8(w0, w1);
    } else {
      const short* W = (const short*)Wv;
      *(short8*)(&sW[lrow][lcol]) = *(const short8*)(W + wrow + k0);
    }
    __syncthreads();

    short8 af[2], bf[2];
#pragma unroll
    for (int i = 0; i < 2; i++) af[i] = *(const short8*)(&sA[wr * 32 + i * 16 + fr][kg]);
#pragma unroll
    for (int n = 0; n < 2; n++) bf[n] = *(const short8*)(&sW[wc * 32 + n * 16 + fr][kg]);

#pragma unroll
    for (int i = 0; i < 2; i++)
#pragma unroll
      for (int n = 0; n < 2; n++)
        acc[i][n] = __builtin_amdgcn_mfma_f32_16x16x32_bf16(af[i], bf[n], acc[i][n], 0, 0, 0);
    __syncthreads();
  }

#pragma unroll
  for (int i = 0; i < 2; i++)
#pragma unroll
    for (int n = 0; n < 2; n++) {
      const int gr = bm * 64 + wr * 32 + i * 16 + ((lane >> 4) << 2);
      const int gc = bn * 64 + wc * 32 + n * 16 + fr;
      const float bv = bias ? bias[gc] : 0.f;
#pragma unroll
      for (int r = 0; r < 4; r++)
        C[(size_t)(gr + r) * ncols + gc] = acc[i][n][r] + bv;
    }
}

// ---------------------------------------------------------------------------
// Normalize memory rows -> mn (bf16) and build memT (fp32, [M][N]).
// ---------------------------------------------------------------------------
__global__ __launch_bounds__(128) void prep_mem(const float* __restrict__ mem,
    short* __restrict__ mn_bf, float* __restrict__ memT)
{
  const int n = blockIdx.x, t = threadIdx.x;
  const int lane = t & 63, wid = t >> 6;
  const float v = mem[n * MDIM + t];
  float ss = v * v;
#pragma unroll
  for (int o = 32; o; o >>= 1) ss += __shfl_xor(ss, o);
  __shared__ float sred[2];
  if (lane == 0) sred[wid] = ss;
  __syncthreads();
  const float inv = 1.f / fmaxf(sqrtf(sred[0] + sred[1]), 1e-8f);
  mn_bf[n * MDIM + t] = (short)f2bfu(v * inv);
  memT[(size_t)t * NDIM + n] = v;
}

// ---------------------------------------------------------------------------
// Normalize k rows: kraw (fp32) -> khat (bf16).
// ---------------------------------------------------------------------------
__global__ __launch_bounds__(128) void knorm(const float* __restrict__ kraw,
                                             short* __restrict__ khat)
{
  const int b = blockIdx.x, t = threadIdx.x;
  const int lane = t & 63, wid = t >> 6;
  const float v = kraw[(size_t)b * MDIM + t];
  float ss = v * v;
#pragma unroll
  for (int o = 32; o; o >>= 1) ss += __shfl_xor(ss, o);
  __shared__ float sred[2];
  if (lane == 0) sred[wid] = ss;
  __syncthreads();
  const float inv = 1.f / fmaxf(sqrtf(sred[0] + sred[1]), 1e-8f);
  khat[(size_t)b * MDIM + t] = (short)f2bfu(v * inv);
}

// ---------------------------------------------------------------------------
// beta / g / gamma: one wave per batch row, three 512-length dots.
// ---------------------------------------------------------------------------
__global__ __launch_bounds__(256) void scalars_k(const float* __restrict__ x,
    const float* __restrict__ Wb, const float* __restrict__ bb,
    const float* __restrict__ Wg, const float* __restrict__ bg,
    const float* __restrict__ Wgam, const float* __restrict__ bgam,
    float* __restrict__ bgg)
{
  const int wid = threadIdx.x >> 6, lane = threadIdx.x & 63;
  const int b = blockIdx.x * 4 + wid;
  const size_t xo = (size_t)b * HDIM + lane * 8;
  const float4 x0 = *(const float4*)(x + xo);
  const float4 x1 = *(const float4*)(x + xo + 4);
  const float4 b0 = *(const float4*)(Wb + lane * 8);
  const float4 b1 = *(const float4*)(Wb + lane * 8 + 4);
  const float4 g0 = *(const float4*)(Wg + lane * 8);
  const float4 g1 = *(const float4*)(Wg + lane * 8 + 4);
  const float4 m0 = *(const float4*)(Wgam + lane * 8);
  const float4 m1 = *(const float4*)(Wgam + lane * 8 + 4);
  float zb = x0.x*b0.x + x0.y*b0.y + x0.z*b0.z + x0.w*b0.w
           + x1.x*b1.x + x1.y*b1.y + x1.z*b1.z + x1.w*b1.w;
  float zg = x0.x*g0.x + x0.y*g0.y + x0.z*g0.z + x0.w*g0.w
           + x1.x*g1.x + x1.y*g1.y + x1.z*g1.z + x1.w*g1.w;
  float zm = x0.x*m0.x + x0.y*m0.y + x0.z*m0.z + x0.w*m0.w
           + x1.x*m1.x + x1.y*m1.y + x1.z*m1.z + x1.w*m1.w;
#pragma unroll
  for (int o = 32; o; o >>= 1) {
    zb += __shfl_xor(zb, o); zg += __shfl_xor(zg, o); zm += __shfl_xor(zm, o);
  }
  if (lane == 0) {
    zb += bb[0]; zg += bg[0]; zm += bgam[0];
    bgg[b * 4 + 0] = softplusf(zb);
    bgg[b * 4 + 1] = 1.f / (1.f + __expf(-zg));
    bgg[b * 4 + 2] = 1.f + softplusf(zm);
  }
}

// ---------------------------------------------------------------------------
// Row pass: softmax(s), softmax(beta*cos), gate, radix-4 FFT circular conv,
// sharpen, normalize.  One 256-thread block per batch row.
// ---------------------------------------------------------------------------
__device__ __forceinline__ float bred_max(float v, float* sred, int lane, int wid) {
#pragma unroll
  for (int o = 32; o; o >>= 1) v = fmaxf(v, __shfl_xor(v, o));
  __syncthreads();
  if (lane == 0) sred[wid] = v;
  __syncthreads();
  return fmaxf(fmaxf(sred[0], sred[1]), fmaxf(sred[2], sred[3]));
}
__device__ __forceinline__ float bred_sum(float v, float* sred, int lane, int wid) {
#pragma unroll
  for (int o = 32; o; o >>= 1) v += __shfl_xor(v, o);
  __syncthreads();
  if (lane == 0) sred[wid] = v;
  __syncthreads();
  return sred[0] + sred[1] + sred[2] + sred[3];
}

__device__ __forceinline__ float2 cmulf(float2 a, float c, float s) {
  return make_float2(a.x * c - a.y * s, a.x * s + a.y * c);
}

// 1024-pt forward DFT (e^{-2pi i nk/N}), radix-4 Stockham DIF, 5 stages.
// Input in x; OUTPUT lands in y.  256 threads, 1 radix-4 butterfly each/stage.
__device__ __forceinline__ void fft1024r4(float2* x, float2* y,
    const float* __restrict__ twc, const float* __restrict__ twn, int tid)
{
  float2* src = x;
  float2* dst = y;
#pragma unroll
  for (int st = 0; st < 5; ++st) {
    const int ls = 2 * st;
    const int s  = 1 << ls;
    const int m  = 256 >> ls;            // ns/4, ns = 1024 >> (2*st)
    const int p  = tid >> ls;
    const int q  = tid & (s - 1);
    const int tb = tid & ~(s - 1);       // p * tws  (tws = 1 << ls2... = s)
    const float2 a0 = src[q + s * p];
    const float2 a1 = src[q + s * (p + m)];
    const float2 a2 = src[q + s * (p + 2 * m)];
    const float2 a3 = src[q + s * (p + 3 * m)];
    const float b0x = a0.x + a2.x, b0y = a0.y + a2.y;
    const float b1x = a1.x + a3.x, b1y = a1.y + a3.y;
    const float b2x = a0.x - a2.x, b2y = a0.y - a2.y;
    const float b3x = a1.x - a3.x, b3y = a1.y - a3.y;
    const float2 A0 = make_float2(b0x + b1x, b0y + b1y);
    const float2 A1 = make_float2(b2x + b3y, b2y - b3x);   // (a0-a2) - i(a1-a3)
    const float2 A2 = make_float2(b0x - b1x, b0y - b1y);
    const float2 A3 = make_float2(b2x - b3y, b2y + b3x);   // (a0-a2) + i(a1-a3)
    const int o = q + 4 * s * p;
    dst[o]         = A0;
    dst[o + s]     = cmulf(A1, twc[tb],     twn[tb]);
    dst[o + 2*s]   = cmulf(A2, twc[2 * tb], twn[2 * tb]);
    dst[o + 3*s]   = cmulf(A3, twc[3 * tb], twn[3 * tb]);
    __syncthreads();
    float2* t = src; src = dst; dst = t;
  }
}

__global__ __launch_bounds__(256) void rowpass(
    const float* __restrict__ slog, const float* __restrict__ cosb,
    const float* __restrict__ bgg, const float* __restrict__ prev,
    float* __restrict__ wout)
{
  __shared__ float2 bufA[1024];
  __shared__ float2 bufB[1024];
  __shared__ float twc[768];
  __shared__ float twn[768];
  __shared__ float sred[4];
  const int b = blockIdx.x, tid = threadIdx.x;
  const int lane = tid & 63, wid = tid >> 6;

  for (int i = tid; i < 768; i += 256) {
    const float ang = -6.283185307179586f * (float)i * (1.0f / 1024.0f);
    float sn, cs; __sincosf(ang, &sn, &cs);
    twc[i] = cs; twn[i] = sn;
  }

  const float beta = bgg[b * 4 + 0], g = bgg[b * 4 + 1], gamma = bgg[b * 4 + 2];

  float sv[4], cv[4];
#pragma unroll
  for (int i = 0; i < 4; i++) {
    sv[i] = slog[(size_t)b * NDIM + tid + i * 256];
    cv[i] = beta * cosb[(size_t)b * NDIM + tid + i * 256];
  }
  // softmax over s logits
  float m1 = bred_max(fmaxf(fmaxf(sv[0], sv[1]), fmaxf(sv[2], sv[3])), sred, lane, wid);
  float e1 = 0.f;
#pragma unroll
  for (int i = 0; i < 4; i++) { sv[i] = __expf(sv[i] - m1); e1 += sv[i]; }
  const float r1 = 1.f / bred_sum(e1, sred, lane, wid);
  // softmax over beta*cos
  float m2 = bred_max(fmaxf(fmaxf(cv[0], cv[1]), fmaxf(cv[2], cv[3])), sred, lane, wid);
  float e2 = 0.f;
#pragma unroll
  for (int i = 0; i < 4; i++) { cv[i] = __expf(cv[i] - m2); e2 += cv[i]; }
  const float r2 = 1.f / bred_sum(e2, sred, lane, wid);

  // gate + pack z = w_g + i*s
#pragma unroll
  for (int i = 0; i < 4; i++) {
    const int idx = tid + i * 256;
    const float wc = cv[i] * r2;
    const float pv = prev[(size_t)b * NDIM + idx];
    const float wg = g * wc + (1.f - g) * pv;
    bufA[idx] = make_float2(wg, sv[i] * r1);
  }
  __syncthreads();

  fft1024r4(bufA, bufB, twc, twn, tid);   // Z in bufB

  // spectral split, multiply, conjugate (prep for ifft-via-forward)
#pragma unroll
  for (int i = 0; i < 4; i++) {
    const int k = tid + i * 256;
    const float2 Zk = bufB[k];
    const float2 Zr = bufB[(1024 - k) & 1023];
    const float2 Wc = make_float2(0.5f * (Zk.x + Zr.x), 0.5f * (Zk.y - Zr.y));
    const float2 Sc = make_float2(0.5f * (Zk.y + Zr.y), 0.5f * (Zr.x - Zk.x));
    const float2 P = make_float2(Wc.x * Sc.x - Wc.y * Sc.y, Wc.x * Sc.y + Wc.y * Sc.x);
    bufA[k] = make_float2(P.x, -P.y);
  }
  __syncthreads();

  fft1024r4(bufA, bufB, twc, twn, tid);   // conj(FFT(conj(P))) in bufB

  // w_t = Re/1024, clamp, sharpen, normalize
  float wt[4]; float esum = 0.f;
#pragma unroll
  for (int i = 0; i < 4; i++) {
    float v = bufB[tid + i * 256].x * (1.f / 1024.f);
    v = fmaxf(v, 0.f);
    const float p = (v > 0.f) ? __expf(gamma * __logf(v)) : 0.f;
    wt[i] = p; esum += p;
  }
  const float rn = 1.f / (bred_sum(esum, sred, lane, wid) + 1e-16f);
#pragma unroll
  for (int i = 0; i < 4; i++)
    wout[(size_t)b * NDIM + tid + i * 256] = wt[i] * rn;
}

// ---------------------------------------------------------------------------
extern "C" void kernel_launch(void* const* d_in, const int* in_sizes, int n_in,
                              void* d_out, int out_size, void* d_ws, size_t ws_size,
                              hipStream_t stream)
{
  const float* x    = (const float*)d_in[0];
  const float* prev = (const float*)d_in[1];
  const float* mem  = (const float*)d_in[2];
  const float* Wk   = (const float*)d_in[3];
  const float* bk   = (const float*)d_in[4];
  const float* Wb   = (const float*)d_in[5];
  const float* bb   = (const float*)d_in[6];
  const float* Wg   = (const float*)d_in[7];
  const float* bg   = (const float*)d_in[8];
  const float* Ws   = (const float*)d_in[9];
  const float* bs   = (const float*)d_in[10];
  const float* Wgam = (const float*)d_in[11];
  const float* bgam = (const float*)d_in[12];

  char* ws = (char*)d_ws;
  short* mn_bf = (short*)(ws + 0);         // 1024*128*2 = 256 KB
  float* memT  = (float*)(ws + 262144);    // 128*1024*4 = 512 KB
  float* kraw  = (float*)(ws + 786432);    // 8192*128*4 = 4 MB
  short* khat  = (short*)(ws + 4980736);   // 8192*128*2 = 2 MB
  float* slog  = (float*)(ws + 7077888);   // 8192*1024*4 = 32 MB
  float* cosb  = (float*)(ws + 40632320);  // 32 MB
  float* bgg   = (float*)(ws + 74186752);  // 8192*4*4 = 128 KB (total ~70.9 MB)

  float* readout = (float*)d_out;                          // [8192][128]
  float* wout = readout + (size_t)B_ROWS * MDIM;           // [8192][1024]

  prep_mem<<<NDIM, MDIM, 0, stream>>>(mem, mn_bf, memT);
  gemm_bt<true, true><<<dim3(MDIM / 64, B_ROWS / 64), 256, 0, stream>>>(
      x, Wk, bk, kraw, MDIM, HDIM);
  gemm_bt<true, true><<<dim3(NDIM / 64, B_ROWS / 64), 256, 0, stream>>>(
      x, Ws, bs, slog, NDIM, HDIM);
  scalars_k<<<B_ROWS / 4, 256, 0, stream>>>(x, Wb, bb, Wg, bg, Wgam, bgam, bgg);
  knorm<<<B_ROWS, MDIM, 0, stream>>>(kraw, khat);
  gemm_bt<false, false><<<dim3(NDIM / 64, B_ROWS / 64), 256, 0, stream>>>(
      khat, mn_bf, nullptr, cosb, NDIM, MDIM);
  rowpass<<<B_ROWS, 256, 0, stream>>>(slog, cosb, bgg, prev, wout);
  gemm_bt<true, true><<<dim3(MDIM / 64, B_ROWS / 64), 256, 0, stream>>>(
      wout, memT, nullptr, readout, MDIM, NDIM);
}

// Round 4
// 151.571 us; speedup vs baseline: 1.1561x; 1.0386x over previous
//
#include <hip/hip_runtime.h>
#include <hip/hip_bf16.h>

typedef __attribute__((ext_vector_type(8))) short short8;
typedef __attribute__((ext_vector_type(4))) float f32x4;

#define B_ROWS 8192
#define HDIM 512
#define NDIM 1024
#define MDIM 128

__device__ __forceinline__ float softplusf(float z) {
  return fmaxf(z, 0.f) + log1pf(__expf(-fabsf(z)));
}
__device__ __forceinline__ unsigned short f2bfu(float f) {
  __hip_bfloat16 h = __float2bfloat16(f);   // round-to-nearest-even
  return *reinterpret_cast<unsigned short*>(&h);
}
__device__ __forceinline__ short8 pack8(float4 a, float4 b) {
  short8 r;
  r[0] = (short)f2bfu(a.x); r[1] = (short)f2bfu(a.y);
  r[2] = (short)f2bfu(a.z); r[3] = (short)f2bfu(a.w);
  r[4] = (short)f2bfu(b.x); r[5] = (short)f2bfu(b.y);
  r[6] = (short)f2bfu(b.z); r[7] = (short)f2bfu(b.w);
  return r;
}

// ---------------------------------------------------------------------------
// 64x64-tile GEMM (kept for skinny outputs): C[m][n] = sum_k A[m][k]*W[n][k]
// (+bias). fp32 operands are packed to bf16 in staging; bf16 native loads.
// ---------------------------------------------------------------------------
template<bool AF32, bool WF32>
__global__ __launch_bounds__(256) void gemm_bt(
    const void* __restrict__ Av, const void* __restrict__ Wv,
    const float* __restrict__ bias, float* __restrict__ C,
    int ncols, int K)
{
  __shared__ __align__(16) short sA[64][40];
  __shared__ __align__(16) short sW[64][40];

  const int tid = threadIdx.x;
  const int bm = blockIdx.y, bn = blockIdx.x;
  const int lrow = tid >> 2;           // 0..63
  const int lcol = (tid & 3) << 3;     // 0,8,16,24
  const int wid = tid >> 6, lane = tid & 63;
  const int wr = wid >> 1, wc = wid & 1;
  const int fr = lane & 15, kg = (lane >> 4) << 3;

  f32x4 acc[2][2] = {};

  const size_t arow = (size_t)(bm * 64 + lrow) * K + lcol;
  const size_t wrow = (size_t)(bn * 64 + lrow) * K + lcol;

  for (int k0 = 0; k0 < K; k0 += 32) {
    if constexpr (AF32) {
      const float* A = (const float*)Av;
      const float4 a0 = *(const float4*)(A + arow + k0);
      const float4 a1 = *(const float4*)(A + arow + k0 + 4);
      *(short8*)(&sA[lrow][lcol]) = pack8(a0, a1);
    } else {
      const short* A = (const short*)Av;
      *(short8*)(&sA[lrow][lcol]) = *(const short8*)(A + arow + k0);
    }
    if constexpr (WF32) {
      const float* W = (const float*)Wv;
      const float4 w0 = *(const float4*)(W + wrow + k0);
      const float4 w1 = *(const float4*)(W + wrow + k0 + 4);
      *(short8*)(&sW[lrow][lcol]) = pack8(w0, w1);
    } else {
      const short* W = (const short*)Wv;
      *(short8*)(&sW[lrow][lcol]) = *(const short8*)(W + wrow + k0);
    }
    __syncthreads();

    short8 af[2], bf[2];
#pragma unroll
    for (int i = 0; i < 2; i++) af[i] = *(const short8*)(&sA[wr * 32 + i * 16 + fr][kg]);
#pragma unroll
    for (int n = 0; n < 2; n++) bf[n] = *(const short8*)(&sW[wc * 32 + n * 16 + fr][kg]);

#pragma unroll
    for (int i = 0; i < 2; i++)
#pragma unroll
      for (int n = 0; n < 2; n++)
        acc[i][n] = __builtin_amdgcn_mfma_f32_16x16x32_bf16(af[i], bf[n], acc[i][n], 0, 0, 0);
    __syncthreads();
  }

#pragma unroll
  for (int i = 0; i < 2; i++)
#pragma unroll
    for (int n = 0; n < 2; n++) {
      const int gr = bm * 64 + wr * 32 + i * 16 + ((lane >> 4) << 2);
      const int gc = bn * 64 + wc * 32 + n * 16 + fr;
      const float bv = bias ? bias[gc] : 0.f;
#pragma unroll
      for (int r = 0; r < 4; r++)
        C[(size_t)(gr + r) * ncols + gc] = acc[i][n][r] + bv;
    }
}

// ---------------------------------------------------------------------------
// 128x128-tile GEMM, 4 waves (2x2 of 64x64), K-step 32.
// fp32 operands: reg-staged fp32->bf16 pack.  bf16 operands: global_load_lds
// width-16 into linear LDS [128][32].
// ---------------------------------------------------------------------------
template<bool AF32, bool WF32>
__global__ __launch_bounds__(256) void kgemm128(
    const void* __restrict__ Av, const void* __restrict__ Wv,
    const float* __restrict__ bias, float* __restrict__ C,
    int ncols, int K)
{
  __shared__ __align__(16) short sA[128 * 32];
  __shared__ __align__(16) short sB[128 * 32];

  const int tid = threadIdx.x, lane = tid & 63, wid = tid >> 6;
  const int bm = blockIdx.y, bn = blockIdx.x;
  const int wr = wid >> 1, wc = wid & 1;
  const int fr = lane & 15, kg = (lane >> 4) << 3;

  f32x4 acc[4][4] = {};

  for (int k0 = 0; k0 < K; k0 += 32) {
    if (k0) __syncthreads();               // protect LDS before overwrite

    if constexpr (AF32) {
      const float* A = (const float*)Av;
      const int row = tid >> 1, c0 = (tid & 1) * 16;
      const float* src = A + (size_t)(bm * 128 + row) * K + k0 + c0;
      const float4 v0 = *(const float4*)src;
      const float4 v1 = *(const float4*)(src + 4);
      const float4 v2 = *(const float4*)(src + 8);
      const float4 v3 = *(const float4*)(src + 12);
      short* d = &sA[row * 32 + c0];
      *(short8*)d = pack8(v0, v1);
      *(short8*)(d + 8) = pack8(v2, v3);
    } else {
      const short* A = (const short*)Av;
#pragma unroll
      for (int j = 0; j < 2; j++) {
        const int c = tid + j * 256;       // 16B chunk id, 0..511
        const short* g = A + (size_t)(bm * 128 + (c >> 2)) * K + k0 + (c & 3) * 8;
        short* l = &sA[(j * 256 + wid * 64) * 8];   // wave-uniform base
        __builtin_amdgcn_global_load_lds(
            (const __attribute__((address_space(1))) void*)g,
            (__attribute__((address_space(3))) void*)l, 16, 0, 0);
      }
    }

    if constexpr (WF32) {
      const float* W = (const float*)Wv;
      const int row = tid >> 1, c0 = (tid & 1) * 16;
      const float* src = W + (size_t)(bn * 128 + row) * K + k0 + c0;
      const float4 v0 = *(const float4*)src;
      const float4 v1 = *(const float4*)(src + 4);
      const float4 v2 = *(const float4*)(src + 8);
      const float4 v3 = *(const float4*)(src + 12);
      short* d = &sB[row * 32 + c0];
      *(short8*)d = pack8(v0, v1);
      *(short8*)(d + 8) = pack8(v2, v3);
    } else {
      const short* W = (const short*)Wv;
#pragma unroll
      for (int j = 0; j < 2; j++) {
        const int c = tid + j * 256;
        const short* g = W + (size_t)(bn * 128 + (c >> 2)) * K + k0 + (c & 3) * 8;
        short* l = &sB[(j * 256 + wid * 64) * 8];
        __builtin_amdgcn_global_load_lds(
            (const __attribute__((address_space(1))) void*)g,
            (__attribute__((address_space(3))) void*)l, 16, 0, 0);
      }
    }
    __syncthreads();

    short8 af[4], bf[4];
#pragma unroll
    for (int m = 0; m < 4; m++)
      af[m] = *(const short8*)(&sA[(wr * 64 + m * 16 + fr) * 32 + kg]);
#pragma unroll
    for (int n = 0; n < 4; n++)
      bf[n] = *(const short8*)(&sB[(wc * 64 + n * 16 + fr) * 32 + kg]);

#pragma unroll
    for (int m = 0; m < 4; m++)
#pragma unroll
      for (int n = 0; n < 4; n++)
        acc[m][n] = __builtin_amdgcn_mfma_f32_16x16x32_bf16(af[m], bf[n], acc[m][n], 0, 0, 0);
  }

#pragma unroll
  for (int m = 0; m < 4; m++)
#pragma unroll
    for (int n = 0; n < 4; n++) {
      const int gr = bm * 128 + wr * 64 + m * 16 + ((lane >> 4) << 2);
      const int gc = bn * 128 + wc * 64 + n * 16 + fr;
      const float bv = bias ? bias[gc] : 0.f;
#pragma unroll
      for (int r = 0; r < 4; r++)
        C[(size_t)(gr + r) * ncols + gc] = acc[m][n][r] + bv;
    }
}

// ---------------------------------------------------------------------------
// Normalize memory rows -> mn (bf16) and build memT (bf16, [M][N]).
// ---------------------------------------------------------------------------
__global__ __launch_bounds__(128) void prep_mem(const float* __restrict__ mem,
    short* __restrict__ mn_bf, short* __restrict__ memT_bf)
{
  const int n = blockIdx.x, t = threadIdx.x;
  const int lane = t & 63, wid = t >> 6;
  const float v = mem[n * MDIM + t];
  float ss = v * v;
#pragma unroll
  for (int o = 32; o; o >>= 1) ss += __shfl_xor(ss, o);
  __shared__ float sred[2];
  if (lane == 0) sred[wid] = ss;
  __syncthreads();
  const float inv = 1.f / fmaxf(sqrtf(sred[0] + sred[1]), 1e-8f);
  mn_bf[n * MDIM + t] = (short)f2bfu(v * inv);
  memT_bf[(size_t)t * NDIM + n] = (short)f2bfu(v);
}

// ---------------------------------------------------------------------------
// Normalize k rows: kraw (fp32) -> khat (bf16).
// ---------------------------------------------------------------------------
__global__ __launch_bounds__(128) void knorm(const float* __restrict__ kraw,
                                             short* __restrict__ khat)
{
  const int b = blockIdx.x, t = threadIdx.x;
  const int lane = t & 63, wid = t >> 6;
  const float v = kraw[(size_t)b * MDIM + t];
  float ss = v * v;
#pragma unroll
  for (int o = 32; o; o >>= 1) ss += __shfl_xor(ss, o);
  __shared__ float sred[2];
  if (lane == 0) sred[wid] = ss;
  __syncthreads();
  const float inv = 1.f / fmaxf(sqrtf(sred[0] + sred[1]), 1e-8f);
  khat[(size_t)b * MDIM + t] = (short)f2bfu(v * inv);
}

// ---------------------------------------------------------------------------
// beta / g / gamma: one wave per batch row, three 512-length dots.
// ---------------------------------------------------------------------------
__global__ __launch_bounds__(256) void scalars_k(const float* __restrict__ x,
    const float* __restrict__ Wb, const float* __restrict__ bb,
    const float* __restrict__ Wg, const float* __restrict__ bg,
    const float* __restrict__ Wgam, const float* __restrict__ bgam,
    float* __restrict__ bgg)
{
  const int wid = threadIdx.x >> 6, lane = threadIdx.x & 63;
  const int b = blockIdx.x * 4 + wid;
  const size_t xo = (size_t)b * HDIM + lane * 8;
  const float4 x0 = *(const float4*)(x + xo);
  const float4 x1 = *(const float4*)(x + xo + 4);
  const float4 b0 = *(const float4*)(Wb + lane * 8);
  const float4 b1 = *(const float4*)(Wb + lane * 8 + 4);
  const float4 g0 = *(const float4*)(Wg + lane * 8);
  const float4 g1 = *(const float4*)(Wg + lane * 8 + 4);
  const float4 m0 = *(const float4*)(Wgam + lane * 8);
  const float4 m1 = *(const float4*)(Wgam + lane * 8 + 4);
  float zb = x0.x*b0.x + x0.y*b0.y + x0.z*b0.z + x0.w*b0.w
           + x1.x*b1.x + x1.y*b1.y + x1.z*b1.z + x1.w*b1.w;
  float zg = x0.x*g0.x + x0.y*g0.y + x0.z*g0.z + x0.w*g0.w
           + x1.x*g1.x + x1.y*g1.y + x1.z*g1.z + x1.w*g1.w;
  float zm = x0.x*m0.x + x0.y*m0.y + x0.z*m0.z + x0.w*m0.w
           + x1.x*m1.x + x1.y*m1.y + x1.z*m1.z + x1.w*m1.w;
#pragma unroll
  for (int o = 32; o; o >>= 1) {
    zb += __shfl_xor(zb, o); zg += __shfl_xor(zg, o); zm += __shfl_xor(zm, o);
  }
  if (lane == 0) {
    zb += bb[0]; zg += bg[0]; zm += bgam[0];
    bgg[b * 4 + 0] = softplusf(zb);
    bgg[b * 4 + 1] = 1.f / (1.f + __expf(-zg));
    bgg[b * 4 + 2] = 1.f + softplusf(zm);
  }
}

// ---------------------------------------------------------------------------
// Row pass: softmax(s), softmax(beta*cos), gate, radix-4 FFT circular conv,
// sharpen, normalize.  One 256-thread block per batch row.
// ---------------------------------------------------------------------------
__device__ __forceinline__ float bred_max(float v, float* sred, int lane, int wid) {
#pragma unroll
  for (int o = 32; o; o >>= 1) v = fmaxf(v, __shfl_xor(v, o));
  __syncthreads();
  if (lane == 0) sred[wid] = v;
  __syncthreads();
  return fmaxf(fmaxf(sred[0], sred[1]), fmaxf(sred[2], sred[3]));
}
__device__ __forceinline__ float bred_sum(float v, float* sred, int lane, int wid) {
#pragma unroll
  for (int o = 32; o; o >>= 1) v += __shfl_xor(v, o);
  __syncthreads();
  if (lane == 0) sred[wid] = v;
  __syncthreads();
  return sred[0] + sred[1] + sred[2] + sred[3];
}

__device__ __forceinline__ float2 cmulf(float2 a, float c, float s) {
  return make_float2(a.x * c - a.y * s, a.x * s + a.y * c);
}

// 1024-pt forward DFT (e^{-2pi i nk/N}), radix-4 Stockham DIF, 5 stages.
// Input in x; OUTPUT lands in y.  256 threads, 1 radix-4 butterfly each/stage.
__device__ __forceinline__ void fft1024r4(float2* x, float2* y,
    const float* __restrict__ twc, const float* __restrict__ twn, int tid)
{
  float2* src = x;
  float2* dst = y;
#pragma unroll
  for (int st = 0; st < 5; ++st) {
    const int ls = 2 * st;
    const int s  = 1 << ls;
    const int m  = 256 >> ls;
    const int p  = tid >> ls;
    const int q  = tid & (s - 1);
    const int tb = tid & ~(s - 1);
    const float2 a0 = src[q + s * p];
    const float2 a1 = src[q + s * (p + m)];
    const float2 a2 = src[q + s * (p + 2 * m)];
    const float2 a3 = src[q + s * (p + 3 * m)];
    const float b0x = a0.x + a2.x, b0y = a0.y + a2.y;
    const float b1x = a1.x + a3.x, b1y = a1.y + a3.y;
    const float b2x = a0.x - a2.x, b2y = a0.y - a2.y;
    const float b3x = a1.x - a3.x, b3y = a1.y - a3.y;
    const float2 A0 = make_float2(b0x + b1x, b0y + b1y);
    const float2 A1 = make_float2(b2x + b3y, b2y - b3x);
    const float2 A2 = make_float2(b0x - b1x, b0y - b1y);
    const float2 A3 = make_float2(b2x - b3y, b2y + b3x);
    const int o = q + 4 * s * p;
    dst[o]         = A0;
    dst[o + s]     = cmulf(A1, twc[tb],     twn[tb]);
    dst[o + 2*s]   = cmulf(A2, twc[2 * tb], twn[2 * tb]);
    dst[o + 3*s]   = cmulf(A3, twc[3 * tb], twn[3 * tb]);
    __syncthreads();
    float2* t = src; src = dst; dst = t;
  }
}

__global__ __launch_bounds__(256) void rowpass(
    const float* __restrict__ slog, const float* __restrict__ cosb,
    const float* __restrict__ bgg, const float* __restrict__ prev,
    float* __restrict__ wout)
{
  __shared__ float2 bufA[1024];
  __shared__ float2 bufB[1024];
  __shared__ float twc[768];
  __shared__ float twn[768];
  __shared__ float sred[4];
  const int b = blockIdx.x, tid = threadIdx.x;
  const int lane = tid & 63, wid = tid >> 6;

  for (int i = tid; i < 768; i += 256) {
    const float ang = -6.283185307179586f * (float)i * (1.0f / 1024.0f);
    float sn, cs; __sincosf(ang, &sn, &cs);
    twc[i] = cs; twn[i] = sn;
  }

  const float beta = bgg[b * 4 + 0], g = bgg[b * 4 + 1], gamma = bgg[b * 4 + 2];

  float sv[4], cv[4];
#pragma unroll
  for (int i = 0; i < 4; i++) {
    sv[i] = slog[(size_t)b * NDIM + tid + i * 256];
    cv[i] = beta * cosb[(size_t)b * NDIM + tid + i * 256];
  }
  float m1 = bred_max(fmaxf(fmaxf(sv[0], sv[1]), fmaxf(sv[2], sv[3])), sred, lane, wid);
  float e1 = 0.f;
#pragma unroll
  for (int i = 0; i < 4; i++) { sv[i] = __expf(sv[i] - m1); e1 += sv[i]; }
  const float r1 = 1.f / bred_sum(e1, sred, lane, wid);
  float m2 = bred_max(fmaxf(fmaxf(cv[0], cv[1]), fmaxf(cv[2], cv[3])), sred, lane, wid);
  float e2 = 0.f;
#pragma unroll
  for (int i = 0; i < 4; i++) { cv[i] = __expf(cv[i] - m2); e2 += cv[i]; }
  const float r2 = 1.f / bred_sum(e2, sred, lane, wid);

#pragma unroll
  for (int i = 0; i < 4; i++) {
    const int idx = tid + i * 256;
    const float wc = cv[i] * r2;
    const float pv = prev[(size_t)b * NDIM + idx];
    const float wg = g * wc + (1.f - g) * pv;
    bufA[idx] = make_float2(wg, sv[i] * r1);
  }
  __syncthreads();

  fft1024r4(bufA, bufB, twc, twn, tid);   // Z in bufB

#pragma unroll
  for (int i = 0; i < 4; i++) {
    const int k = tid + i * 256;
    const float2 Zk = bufB[k];
    const float2 Zr = bufB[(1024 - k) & 1023];
    const float2 Wc = make_float2(0.5f * (Zk.x + Zr.x), 0.5f * (Zk.y - Zr.y));
    const float2 Sc = make_float2(0.5f * (Zk.y + Zr.y), 0.5f * (Zr.x - Zk.x));
    const float2 P = make_float2(Wc.x * Sc.x - Wc.y * Sc.y, Wc.x * Sc.y + Wc.y * Sc.x);
    bufA[k] = make_float2(P.x, -P.y);
  }
  __syncthreads();

  fft1024r4(bufA, bufB, twc, twn, tid);   // conj(FFT(conj(P))) in bufB

  float wt[4]; float esum = 0.f;
#pragma unroll
  for (int i = 0; i < 4; i++) {
    float v = bufB[tid + i * 256].x * (1.f / 1024.f);
    v = fmaxf(v, 0.f);
    const float p = (v > 0.f) ? __expf(gamma * __logf(v)) : 0.f;
    wt[i] = p; esum += p;
  }
  const float rn = 1.f / (bred_sum(esum, sred, lane, wid) + 1e-16f);
#pragma unroll
  for (int i = 0; i < 4; i++)
    wout[(size_t)b * NDIM + tid + i * 256] = wt[i] * rn;
}

// ---------------------------------------------------------------------------
extern "C" void kernel_launch(void* const* d_in, const int* in_sizes, int n_in,
                              void* d_out, int out_size, void* d_ws, size_t ws_size,
                              hipStream_t stream)
{
  const float* x    = (const float*)d_in[0];
  const float* prev = (const float*)d_in[1];
  const float* mem  = (const float*)d_in[2];
  const float* Wk   = (const float*)d_in[3];
  const float* bk   = (const float*)d_in[4];
  const float* Wb   = (const float*)d_in[5];
  const float* bb   = (const float*)d_in[6];
  const float* Wg   = (const float*)d_in[7];
  const float* bg   = (const float*)d_in[8];
  const float* Ws   = (const float*)d_in[9];
  const float* bs   = (const float*)d_in[10];
  const float* Wgam = (const float*)d_in[11];
  const float* bgam = (const float*)d_in[12];

  char* ws = (char*)d_ws;
  short* mn_bf   = (short*)(ws + 0);         // 1024*128*2 = 256 KB
  short* memT_bf = (short*)(ws + 262144);    // 128*1024*2 = 256 KB
  float* kraw    = (float*)(ws + 524288);    // 8192*128*4 = 4 MB
  short* khat    = (short*)(ws + 4718592);   // 8192*128*2 = 2 MB
  float* slog    = (float*)(ws + 6815744);   // 8192*1024*4 = 32 MB
  float* cosb    = (float*)(ws + 40370176);  // 32 MB
  float* bgg     = (float*)(ws + 73924608);  // 8192*4*4 = 128 KB (total ~70.6 MB)

  float* readout = (float*)d_out;                          // [8192][128]
  float* wout = readout + (size_t)B_ROWS * MDIM;           // [8192][1024]

  prep_mem<<<NDIM, MDIM, 0, stream>>>(mem, mn_bf, memT_bf);
  gemm_bt<true, true><<<dim3(MDIM / 64, B_ROWS / 64), 256, 0, stream>>>(
      x, Wk, bk, kraw, MDIM, HDIM);
  kgemm128<true, true><<<dim3(NDIM / 128, B_ROWS / 128), 256, 0, stream>>>(
      x, Ws, bs, slog, NDIM, HDIM);
  scalars_k<<<B_ROWS / 4, 256, 0, stream>>>(x, Wb, bb, Wg, bg, Wgam, bgam, bgg);
  knorm<<<B_ROWS, MDIM, 0, stream>>>(kraw, khat);
  kgemm128<false, false><<<dim3(NDIM / 128, B_ROWS / 128), 256, 0, stream>>>(
      khat, mn_bf, nullptr, cosb, NDIM, MDIM);
  rowpass<<<B_ROWS, 256, 0, stream>>>(slog, cosb, bgg, prev, wout);
  gemm_bt<true, false><<<dim3(MDIM / 64, B_ROWS / 64), 256, 0, stream>>>(
      wout, memT_bf, nullptr, readout, MDIM, NDIM);
}

// Round 5
// 140.676 us; speedup vs baseline: 1.2457x; 1.0775x over previous
//
#include <hip/hip_runtime.h>
#include <hip/hip_bf16.h>

typedef __attribute__((ext_vector_type(8))) short short8;
typedef __attribute__((ext_vector_type(4))) short short4v;
typedef __attribute__((ext_vector_type(4))) float f32x4;

#define B_ROWS 8192
#define HDIM 512
#define NDIM 1024
#define MDIM 128

__device__ __forceinline__ float softplusf(float z) {
  return fmaxf(z, 0.f) + log1pf(__expf(-fabsf(z)));
}
__device__ __forceinline__ unsigned short f2bfu(float f) {
  __hip_bfloat16 h = __float2bfloat16(f);   // round-to-nearest-even
  return *reinterpret_cast<unsigned short*>(&h);
}
__device__ __forceinline__ short8 pack8(float4 a, float4 b) {
  short8 r;
  r[0] = (short)f2bfu(a.x); r[1] = (short)f2bfu(a.y);
  r[2] = (short)f2bfu(a.z); r[3] = (short)f2bfu(a.w);
  r[4] = (short)f2bfu(b.x); r[5] = (short)f2bfu(b.y);
  r[6] = (short)f2bfu(b.z); r[7] = (short)f2bfu(b.w);
  return r;
}
__device__ __forceinline__ int pad(int i) { return i + (i >> 5); }

// ---------------------------------------------------------------------------
// fp32 -> bf16 pre-pack of x, Ws, Wk (one dispatch).
// ---------------------------------------------------------------------------
__global__ __launch_bounds__(256) void prepack3(
    const float* __restrict__ x, const float* __restrict__ Ws,
    const float* __restrict__ Wk, short* __restrict__ xb,
    short* __restrict__ wsb, short* __restrict__ wkb)
{
  const int NX = B_ROWS * HDIM / 4;   // float4 counts
  const int NS = NDIM * HDIM / 4;
  const int NK = MDIM * HDIM / 4;
  const int stride = gridDim.x * 256;
  for (int i = blockIdx.x * 256 + threadIdx.x; i < NX + NS + NK; i += stride) {
    const float* src; short* dst; int j = i;
    if (j < NX) { src = x; dst = xb; }
    else if (j < NX + NS) { j -= NX; src = Ws; dst = wsb; }
    else { j -= NX + NS; src = Wk; dst = wkb; }
    const float4 v = ((const float4*)src)[j];
    short4v o;
    o[0] = (short)f2bfu(v.x); o[1] = (short)f2bfu(v.y);
    o[2] = (short)f2bfu(v.z); o[3] = (short)f2bfu(v.w);
    ((short4v*)dst)[j] = o;
  }
}

// ---------------------------------------------------------------------------
// 64x64-tile GEMM: C[m][n] = sum_k A[m][k]*W[n][k] (+bias). fp32 operands are
// packed to bf16 in staging; bf16 operands load native.
// ---------------------------------------------------------------------------
template<bool AF32, bool WF32>
__global__ __launch_bounds__(256) void gemm_bt(
    const void* __restrict__ Av, const void* __restrict__ Wv,
    const float* __restrict__ bias, float* __restrict__ C,
    int ncols, int K)
{
  __shared__ __align__(16) short sA[64][40];
  __shared__ __align__(16) short sW[64][40];

  const int tid = threadIdx.x;
  const int bm = blockIdx.y, bn = blockIdx.x;
  const int lrow = tid >> 2;
  const int lcol = (tid & 3) << 3;
  const int wid = tid >> 6, lane = tid & 63;
  const int wr = wid >> 1, wc = wid & 1;
  const int fr = lane & 15, kg = (lane >> 4) << 3;

  f32x4 acc[2][2] = {};

  const size_t arow = (size_t)(bm * 64 + lrow) * K + lcol;
  const size_t wrow = (size_t)(bn * 64 + lrow) * K + lcol;

  for (int k0 = 0; k0 < K; k0 += 32) {
    if constexpr (AF32) {
      const float* A = (const float*)Av;
      const float4 a0 = *(const float4*)(A + arow + k0);
      const float4 a1 = *(const float4*)(A + arow + k0 + 4);
      *(short8*)(&sA[lrow][lcol]) = pack8(a0, a1);
    } else {
      const short* A = (const short*)Av;
      *(short8*)(&sA[lrow][lcol]) = *(const short8*)(A + arow + k0);
    }
    if constexpr (WF32) {
      const float* W = (const float*)Wv;
      const float4 w0 = *(const float4*)(W + wrow + k0);
      const float4 w1 = *(const float4*)(W + wrow + k0 + 4);
      *(short8*)(&sW[lrow][lcol]) = pack8(w0, w1);
    } else {
      const short* W = (const short*)Wv;
      *(short8*)(&sW[lrow][lcol]) = *(const short8*)(W + wrow + k0);
    }
    __syncthreads();

    short8 af[2], bf[2];
#pragma unroll
    for (int i = 0; i < 2; i++) af[i] = *(const short8*)(&sA[wr * 32 + i * 16 + fr][kg]);
#pragma unroll
    for (int n = 0; n < 2; n++) bf[n] = *(const short8*)(&sW[wc * 32 + n * 16 + fr][kg]);

#pragma unroll
    for (int i = 0; i < 2; i++)
#pragma unroll
      for (int n = 0; n < 2; n++)
        acc[i][n] = __builtin_amdgcn_mfma_f32_16x16x32_bf16(af[i], bf[n], acc[i][n], 0, 0, 0);
    __syncthreads();
  }

#pragma unroll
  for (int i = 0; i < 2; i++)
#pragma unroll
    for (int n = 0; n < 2; n++) {
      const int gr = bm * 64 + wr * 32 + i * 16 + ((lane >> 4) << 2);
      const int gc = bn * 64 + wc * 32 + n * 16 + fr;
      const float bv = bias ? bias[gc] : 0.f;
#pragma unroll
      for (int r = 0; r < 4; r++)
        C[(size_t)(gr + r) * ncols + gc] = acc[i][n][r] + bv;
    }
}

// ---------------------------------------------------------------------------
// 128x128-tile GEMM, 4 waves (2x2 of 64x64), K-step 32.
// fp32 operands: reg-staged pack.  bf16: global_load_lds width-16, linear LDS.
// ---------------------------------------------------------------------------
template<bool AF32, bool WF32>
__global__ __launch_bounds__(256) void kgemm128(
    const void* __restrict__ Av, const void* __restrict__ Wv,
    const float* __restrict__ bias, float* __restrict__ C,
    int ncols, int K)
{
  __shared__ __align__(16) short sA[128 * 32];
  __shared__ __align__(16) short sB[128 * 32];

  const int tid = threadIdx.x, lane = tid & 63, wid = tid >> 6;
  const int bm = blockIdx.y, bn = blockIdx.x;
  const int wr = wid >> 1, wc = wid & 1;
  const int fr = lane & 15, kg = (lane >> 4) << 3;

  f32x4 acc[4][4] = {};

  for (int k0 = 0; k0 < K; k0 += 32) {
    if (k0) __syncthreads();

    if constexpr (AF32) {
      const float* A = (const float*)Av;
      const int row = tid >> 1, c0 = (tid & 1) * 16;
      const float* src = A + (size_t)(bm * 128 + row) * K + k0 + c0;
      const float4 v0 = *(const float4*)src;
      const float4 v1 = *(const float4*)(src + 4);
      const float4 v2 = *(const float4*)(src + 8);
      const float4 v3 = *(const float4*)(src + 12);
      short* d = &sA[row * 32 + c0];
      *(short8*)d = pack8(v0, v1);
      *(short8*)(d + 8) = pack8(v2, v3);
    } else {
      const short* A = (const short*)Av;
#pragma unroll
      for (int j = 0; j < 2; j++) {
        const int c = tid + j * 256;
        const short* g = A + (size_t)(bm * 128 + (c >> 2)) * K + k0 + (c & 3) * 8;
        short* l = &sA[(j * 256 + wid * 64) * 8];
        __builtin_amdgcn_global_load_lds(
            (const __attribute__((address_space(1))) void*)g,
            (__attribute__((address_space(3))) void*)l, 16, 0, 0);
      }
    }

    if constexpr (WF32) {
      const float* W = (const float*)Wv;
      const int row = tid >> 1, c0 = (tid & 1) * 16;
      const float* src = W + (size_t)(bn * 128 + row) * K + k0 + c0;
      const float4 v0 = *(const float4*)src;
      const float4 v1 = *(const float4*)(src + 4);
      const float4 v2 = *(const float4*)(src + 8);
      const float4 v3 = *(const float4*)(src + 12);
      short* d = &sB[row * 32 + c0];
      *(short8*)d = pack8(v0, v1);
      *(short8*)(d + 8) = pack8(v2, v3);
    } else {
      const short* W = (const short*)Wv;
#pragma unroll
      for (int j = 0; j < 2; j++) {
        const int c = tid + j * 256;
        const short* g = W + (size_t)(bn * 128 + (c >> 2)) * K + k0 + (c & 3) * 8;
        short* l = &sB[(j * 256 + wid * 64) * 8];
        __builtin_amdgcn_global_load_lds(
            (const __attribute__((address_space(1))) void*)g,
            (__attribute__((address_space(3))) void*)l, 16, 0, 0);
      }
    }
    __syncthreads();

    short8 af[4], bf[4];
#pragma unroll
    for (int m = 0; m < 4; m++)
      af[m] = *(const short8*)(&sA[(wr * 64 + m * 16 + fr) * 32 + kg]);
#pragma unroll
    for (int n = 0; n < 4; n++)
      bf[n] = *(const short8*)(&sB[(wc * 64 + n * 16 + fr) * 32 + kg]);

#pragma unroll
    for (int m = 0; m < 4; m++)
#pragma unroll
      for (int n = 0; n < 4; n++)
        acc[m][n] = __builtin_amdgcn_mfma_f32_16x16x32_bf16(af[m], bf[n], acc[m][n], 0, 0, 0);
  }

#pragma unroll
  for (int m = 0; m < 4; m++)
#pragma unroll
    for (int n = 0; n < 4; n++) {
      const int gr = bm * 128 + wr * 64 + m * 16 + ((lane >> 4) << 2);
      const int gc = bn * 128 + wc * 64 + n * 16 + fr;
      const float bv = bias ? bias[gc] : 0.f;
#pragma unroll
      for (int r = 0; r < 4; r++)
        C[(size_t)(gr + r) * ncols + gc] = acc[m][n][r] + bv;
    }
}

// ---------------------------------------------------------------------------
// Normalize memory rows -> mn (bf16) and build memT (bf16, [M][N]).
// ---------------------------------------------------------------------------
__global__ __launch_bounds__(128) void prep_mem(const float* __restrict__ mem,
    short* __restrict__ mn_bf, short* __restrict__ memT_bf)
{
  const int n = blockIdx.x, t = threadIdx.x;
  const int lane = t & 63, wid = t >> 6;
  const float v = mem[n * MDIM + t];
  float ss = v * v;
#pragma unroll
  for (int o = 32; o; o >>= 1) ss += __shfl_xor(ss, o);
  __shared__ float sred[2];
  if (lane == 0) sred[wid] = ss;
  __syncthreads();
  const float inv = 1.f / fmaxf(sqrtf(sred[0] + sred[1]), 1e-8f);
  mn_bf[n * MDIM + t] = (short)f2bfu(v * inv);
  memT_bf[(size_t)t * NDIM + n] = (short)f2bfu(v);
}

// ---------------------------------------------------------------------------
// Normalize k rows: kraw (fp32) -> khat (bf16).
// ---------------------------------------------------------------------------
__global__ __launch_bounds__(128) void knorm(const float* __restrict__ kraw,
                                             short* __restrict__ khat)
{
  const int b = blockIdx.x, t = threadIdx.x;
  const int lane = t & 63, wid = t >> 6;
  const float v = kraw[(size_t)b * MDIM + t];
  float ss = v * v;
#pragma unroll
  for (int o = 32; o; o >>= 1) ss += __shfl_xor(ss, o);
  __shared__ float sred[2];
  if (lane == 0) sred[wid] = ss;
  __syncthreads();
  const float inv = 1.f / fmaxf(sqrtf(sred[0] + sred[1]), 1e-8f);
  khat[(size_t)b * MDIM + t] = (short)f2bfu(v * inv);
}

// ---------------------------------------------------------------------------
// beta / g / gamma: one wave per batch row, three 512-length dots.
// ---------------------------------------------------------------------------
__global__ __launch_bounds__(256) void scalars_k(const float* __restrict__ x,
    const float* __restrict__ Wb, const float* __restrict__ bb,
    const float* __restrict__ Wg, const float* __restrict__ bg,
    const float* __restrict__ Wgam, const float* __restrict__ bgam,
    float* __restrict__ bgg)
{
  const int wid = threadIdx.x >> 6, lane = threadIdx.x & 63;
  const int b = blockIdx.x * 4 + wid;
  const size_t xo = (size_t)b * HDIM + lane * 8;
  const float4 x0 = *(const float4*)(x + xo);
  const float4 x1 = *(const float4*)(x + xo + 4);
  const float4 b0 = *(const float4*)(Wb + lane * 8);
  const float4 b1 = *(const float4*)(Wb + lane * 8 + 4);
  const float4 g0 = *(const float4*)(Wg + lane * 8);
  const float4 g1 = *(const float4*)(Wg + lane * 8 + 4);
  const float4 m0 = *(const float4*)(Wgam + lane * 8);
  const float4 m1 = *(const float4*)(Wgam + lane * 8 + 4);
  float zb = x0.x*b0.x + x0.y*b0.y + x0.z*b0.z + x0.w*b0.w
           + x1.x*b1.x + x1.y*b1.y + x1.z*b1.z + x1.w*b1.w;
  float zg = x0.x*g0.x + x0.y*g0.y + x0.z*g0.z + x0.w*g0.w
           + x1.x*g1.x + x1.y*g1.y + x1.z*g1.z + x1.w*g1.w;
  float zm = x0.x*m0.x + x0.y*m0.y + x0.z*m0.z + x0.w*m0.w
           + x1.x*m1.x + x1.y*m1.y + x1.z*m1.z + x1.w*m1.w;
#pragma unroll
  for (int o = 32; o; o >>= 1) {
    zb += __shfl_xor(zb, o); zg += __shfl_xor(zg, o); zm += __shfl_xor(zm, o);
  }
  if (lane == 0) {
    zb += bb[0]; zg += bg[0]; zm += bgam[0];
    bgg[b * 4 + 0] = softplusf(zb);
    bgg[b * 4 + 1] = 1.f / (1.f + __expf(-zg));
    bgg[b * 4 + 2] = 1.f + softplusf(zm);
  }
}

// ---------------------------------------------------------------------------
// 1024-pt forward DFT, radix-4 Stockham DIF, split re/im arrays, padded
// indexing (pad(i) = i + (i>>5)) to kill the 8/16-way store bank conflicts.
// Input in (r0,i0); output in (r1,i1).  Stage-4 twiddles are (1,0): skipped.
// ---------------------------------------------------------------------------
__device__ __forceinline__ void fft1024r4(
    float* r0, float* i0_, float* r1, float* i1_,
    const float* __restrict__ twc, const float* __restrict__ twn, int tid)
{
  float* sr = r0; float* si = i0_;
  float* dr = r1; float* di = i1_;
  const int j0 = pad(tid), j1 = pad(tid + 256), j2 = pad(tid + 512), j3 = pad(tid + 768);
#pragma unroll
  for (int st = 0; st < 5; ++st) {
    const int ls = 2 * st, s = 1 << ls;
    const int p = tid >> ls, q = tid & (s - 1), tb = tid & ~(s - 1);
    const float a0r = sr[j0], a0i = si[j0];
    const float a1r = sr[j1], a1i = si[j1];
    const float a2r = sr[j2], a2i = si[j2];
    const float a3r = sr[j3], a3i = si[j3];
    const float b0r = a0r + a2r, b0i = a0i + a2i;
    const float b1r = a1r + a3r, b1i = a1i + a3i;
    const float b2r = a0r - a2r, b2i = a0i - a2i;
    const float b3r = a1r - a3r, b3i = a1i - a3i;
    const float A0r = b0r + b1r, A0i = b0i + b1i;
    const float A1r = b2r + b3i, A1i = b2i - b3r;   // (a0-a2) - i(a1-a3)
    const float A2r = b0r - b1r, A2i = b0i - b1i;
    const float A3r = b2r - b3i, A3i = b2i + b3r;   // (a0-a2) + i(a1-a3)
    const int o = q + 4 * s * p;
    dr[pad(o)] = A0r; di[pad(o)] = A0i;
    if (st < 4) {
      const float c1 = twc[tb],     s1 = twn[tb];
      const float c2 = twc[2 * tb], s2 = twn[2 * tb];
      const float c3 = twc[3 * tb], s3 = twn[3 * tb];
      dr[pad(o + s)]     = A1r * c1 - A1i * s1; di[pad(o + s)]     = A1r * s1 + A1i * c1;
      dr[pad(o + 2 * s)] = A2r * c2 - A2i * s2; di[pad(o + 2 * s)] = A2r * s2 + A2i * c2;
      dr[pad(o + 3 * s)] = A3r * c3 - A3i * s3; di[pad(o + 3 * s)] = A3r * s3 + A3i * c3;
    } else {
      dr[pad(o + s)]     = A1r; di[pad(o + s)]     = A1i;
      dr[pad(o + 2 * s)] = A2r; di[pad(o + 2 * s)] = A2i;
      dr[pad(o + 3 * s)] = A3r; di[pad(o + 3 * s)] = A3i;
    }
    __syncthreads();
    float* t;
    t = sr; sr = dr; dr = t;
    t = si; si = di; di = t;
  }
}

// ---------------------------------------------------------------------------
// Row pass: softmax(s), softmax(beta*cos) (no max-sub needed: |logits|<~15),
// gate, FFT circular conv, sharpen, normalize.  One 256-thr block per row.
// ---------------------------------------------------------------------------
__global__ __launch_bounds__(256) void rowpass(
    const float* __restrict__ slog, const float* __restrict__ cosb,
    const float* __restrict__ bgg, const float* __restrict__ prev,
    float* __restrict__ wout)
{
  __shared__ float sR0[1056], sI0[1056], sR1[1056], sI1[1056];
  __shared__ float twc[768], twn[768];
  __shared__ float sred[8];
  const int b = blockIdx.x, tid = threadIdx.x;
  const int lane = tid & 63, wid = tid >> 6;

  for (int i = tid; i < 768; i += 256) {
    const float ang = -6.283185307179586f * (float)i * (1.0f / 1024.0f);
    float sn, cs; __sincosf(ang, &sn, &cs);
    twc[i] = cs; twn[i] = sn;
  }

  const float beta = bgg[b * 4 + 0], g = bgg[b * 4 + 1], gamma = bgg[b * 4 + 2];

  float sv[4], cv[4];
  float e1 = 0.f, e2 = 0.f;
#pragma unroll
  for (int i = 0; i < 4; i++) {
    sv[i] = __expf(slog[(size_t)b * NDIM + tid + i * 256]);
    cv[i] = __expf(beta * cosb[(size_t)b * NDIM + tid + i * 256]);
    e1 += sv[i]; e2 += cv[i];
  }
#pragma unroll
  for (int o = 32; o; o >>= 1) { e1 += __shfl_xor(e1, o); e2 += __shfl_xor(e2, o); }
  if (lane == 0) { sred[wid * 2] = e1; sred[wid * 2 + 1] = e2; }
  __syncthreads();
  const float r1 = 1.f / (sred[0] + sred[2] + sred[4] + sred[6]);
  const float r2 = 1.f / (sred[1] + sred[3] + sred[5] + sred[7]);

  // gate + pack z = w_g + i*s into buf0
#pragma unroll
  for (int i = 0; i < 4; i++) {
    const int idx = tid + i * 256;
    const float pv = prev[(size_t)b * NDIM + idx];
    const float wg = g * cv[i] * r2 + (1.f - g) * pv;
    sR0[pad(idx)] = wg;
    sI0[pad(idx)] = sv[i] * r1;
  }
  __syncthreads();

  fft1024r4(sR0, sI0, sR1, sI1, twc, twn, tid);   // Z in buf1

  // spectral split, multiply, conjugate -> buf0
#pragma unroll
  for (int i = 0; i < 4; i++) {
    const int k = tid + i * 256;
    const int kp = pad(k), rp = pad((1024 - k) & 1023);
    const float Zkr = sR1[kp], Zki = sI1[kp];
    const float Zrr = sR1[rp], Zri = sI1[rp];
    const float Wr = 0.5f * (Zkr + Zrr), Wi = 0.5f * (Zki - Zri);
    const float Sr = 0.5f * (Zki + Zri), Si = 0.5f * (Zrr - Zkr);
    sR0[kp] = Wr * Sr - Wi * Si;
    sI0[kp] = -(Wr * Si + Wi * Sr);
  }
  __syncthreads();

  fft1024r4(sR0, sI0, sR1, sI1, twc, twn, tid);   // conj(FFT(conj(P))) in buf1

  // w_t = Re/1024, clamp, sharpen, normalize
  float wt[4]; float esum = 0.f;
#pragma unroll
  for (int i = 0; i < 4; i++) {
    float v = sR1[pad(tid + i * 256)] * (1.f / 1024.f);
    v = fmaxf(v, 0.f);
    const float p = (v > 0.f) ? __expf(gamma * __logf(v)) : 0.f;
    wt[i] = p; esum += p;
  }
#pragma unroll
  for (int o = 32; o; o >>= 1) esum += __shfl_xor(esum, o);
  if (lane == 0) sred[wid] = esum;
  __syncthreads();
  const float rn = 1.f / (sred[0] + sred[1] + sred[2] + sred[3] + 1e-16f);
#pragma unroll
  for (int i = 0; i < 4; i++)
    wout[(size_t)b * NDIM + tid + i * 256] = wt[i] * rn;
}

// ---------------------------------------------------------------------------
extern "C" void kernel_launch(void* const* d_in, const int* in_sizes, int n_in,
                              void* d_out, int out_size, void* d_ws, size_t ws_size,
                              hipStream_t stream)
{
  const float* x    = (const float*)d_in[0];
  const float* prev = (const float*)d_in[1];
  const float* mem  = (const float*)d_in[2];
  const float* Wk   = (const float*)d_in[3];
  const float* bk   = (const float*)d_in[4];
  const float* Wb   = (const float*)d_in[5];
  const float* bb   = (const float*)d_in[6];
  const float* Wg   = (const float*)d_in[7];
  const float* bg   = (const float*)d_in[8];
  const float* Ws   = (const float*)d_in[9];
  const float* bs   = (const float*)d_in[10];
  const float* Wgam = (const float*)d_in[11];
  const float* bgam = (const float*)d_in[12];

  // Lifetime-aliased workspace (stream is sequential; aliasing is static):
  //   xb/wsb/wkb die after slog GEMM, kraw dies after knorm — all before the
  //   cos GEMM writes cosb, so they live INSIDE the cosb region.
  char* ws = (char*)d_ws;
  short* mn_bf   = (short*)(ws + 0);          //  256 KB
  short* memT_bf = (short*)(ws + 262144);     //  256 KB
  short* khat    = (short*)(ws + 524288);     //    2 MB
  float* bgg     = (float*)(ws + 2621440);    //  128 KB
  float* slog    = (float*)(ws + 2752512);    //   32 MB
  float* cosb    = (float*)(ws + 36306944);   //   32 MB  (ends 69,861,376)
  short* xb      = (short*)(ws + 36306944);   //    8 MB  } alias inside cosb
  short* wsb     = (short*)(ws + 44695552);   //    1 MB  }
  short* wkb     = (short*)(ws + 45744128);   //  128 KB  }
  float* kraw    = (float*)(ws + 45875200);   //    4 MB  }

  float* readout = (float*)d_out;                  // [8192][128]
  float* wout = readout + (size_t)B_ROWS * MDIM;   // [8192][1024]

  prepack3<<<2048, 256, 0, stream>>>(x, Ws, Wk, xb, wsb, wkb);
  prep_mem<<<NDIM, MDIM, 0, stream>>>(mem, mn_bf, memT_bf);
  gemm_bt<false, false><<<dim3(MDIM / 64, B_ROWS / 64), 256, 0, stream>>>(
      xb, wkb, bk, kraw, MDIM, HDIM);
  kgemm128<false, false><<<dim3(NDIM / 128, B_ROWS / 128), 256, 0, stream>>>(
      xb, wsb, bs, slog, NDIM, HDIM);
  scalars_k<<<B_ROWS / 4, 256, 0, stream>>>(x, Wb, bb, Wg, bg, Wgam, bgam, bgg);
  knorm<<<B_ROWS, MDIM, 0, stream>>>(kraw, khat);
  kgemm128<false, false><<<dim3(NDIM / 128, B_ROWS / 128), 256, 0, stream>>>(
      khat, mn_bf, nullptr, cosb, NDIM, MDIM);
  rowpass<<<B_ROWS, 256, 0, stream>>>(slog, cosb, bgg, prev, wout);
  gemm_bt<true, false><<<dim3(MDIM / 64, B_ROWS / 64), 256, 0, stream>>>(
      wout, memT_bf, nullptr, readout, MDIM, NDIM);
}

// Round 6
// 128.509 us; speedup vs baseline: 1.3636x; 1.0947x over previous
//
#include <hip/hip_runtime.h>
#include <hip/hip_bf16.h>

typedef __attribute__((ext_vector_type(8))) short short8;
typedef __attribute__((ext_vector_type(4))) short short4v;
typedef __attribute__((ext_vector_type(4))) float f32x4;

#define B_ROWS 8192
#define HDIM 512
#define NDIM 1024
#define MDIM 128

__device__ __forceinline__ float softplusf(float z) {
  return fmaxf(z, 0.f) + log1pf(__expf(-fabsf(z)));
}
__device__ __forceinline__ unsigned short f2bfu(float f) {
  __hip_bfloat16 h = __float2bfloat16(f);   // round-to-nearest-even
  return *reinterpret_cast<unsigned short*>(&h);
}
__device__ __forceinline__ short8 pack8(float4 a, float4 b) {
  short8 r;
  r[0] = (short)f2bfu(a.x); r[1] = (short)f2bfu(a.y);
  r[2] = (short)f2bfu(a.z); r[3] = (short)f2bfu(a.w);
  r[4] = (short)f2bfu(b.x); r[5] = (short)f2bfu(b.y);
  r[6] = (short)f2bfu(b.z); r[7] = (short)f2bfu(b.w);
  return r;
}
__device__ __forceinline__ int pad(int i) { return i + (i >> 4); }

// ---------------------------------------------------------------------------
// Merged prologue: prep_mem (blocks 0..511, 2 rows each), scalars (512..2559),
// fp32->bf16 prepack of x/Ws/Wk (2560..3583, grid-stride).
// ---------------------------------------------------------------------------
__global__ __launch_bounds__(256) void prep_all(
    const float* __restrict__ x, const float* __restrict__ Ws,
    const float* __restrict__ Wk, const float* __restrict__ mem,
    const float* __restrict__ Wb, const float* __restrict__ bb,
    const float* __restrict__ Wg, const float* __restrict__ bg,
    const float* __restrict__ Wgam, const float* __restrict__ bgam,
    short* __restrict__ xb, short* __restrict__ wsb, short* __restrict__ wkb,
    short* __restrict__ mn_bf, short* __restrict__ memT_bf,
    float* __restrict__ bgg)
{
  const int blk = blockIdx.x, t = threadIdx.x;
  if (blk < 512) {
    __shared__ float sredp[4];
    const int half = t >> 7, tl = t & 127;
    const int n = blk * 2 + half;
    const int wid = t >> 6;
    const float v = mem[n * MDIM + tl];
    float ss = v * v;
#pragma unroll
    for (int o = 32; o; o >>= 1) ss += __shfl_xor(ss, o);
    if ((t & 63) == 0) sredp[wid] = ss;
    __syncthreads();
    const float inv = 1.f / fmaxf(sqrtf(sredp[half * 2] + sredp[half * 2 + 1]), 1e-8f);
    mn_bf[n * MDIM + tl] = (short)f2bfu(v * inv);
    memT_bf[(size_t)tl * NDIM + n] = (short)f2bfu(v);
  } else if (blk < 2560) {
    const int wid = t >> 6, lane = t & 63;
    const int b = (blk - 512) * 4 + wid;
    const size_t xo = (size_t)b * HDIM + lane * 8;
    const float4 x0 = *(const float4*)(x + xo);
    const float4 x1 = *(const float4*)(x + xo + 4);
    const float4 b0 = *(const float4*)(Wb + lane * 8);
    const float4 b1 = *(const float4*)(Wb + lane * 8 + 4);
    const float4 g0 = *(const float4*)(Wg + lane * 8);
    const float4 g1 = *(const float4*)(Wg + lane * 8 + 4);
    const float4 m0 = *(const float4*)(Wgam + lane * 8);
    const float4 m1 = *(const float4*)(Wgam + lane * 8 + 4);
    float zb = x0.x*b0.x + x0.y*b0.y + x0.z*b0.z + x0.w*b0.w
             + x1.x*b1.x + x1.y*b1.y + x1.z*b1.z + x1.w*b1.w;
    float zg = x0.x*g0.x + x0.y*g0.y + x0.z*g0.z + x0.w*g0.w
             + x1.x*g1.x + x1.y*g1.y + x1.z*g1.z + x1.w*g1.w;
    float zm = x0.x*m0.x + x0.y*m0.y + x0.z*m0.z + x0.w*m0.w
             + x1.x*m1.x + x1.y*m1.y + x1.z*m1.z + x1.w*m1.w;
#pragma unroll
    for (int o = 32; o; o >>= 1) {
      zb += __shfl_xor(zb, o); zg += __shfl_xor(zg, o); zm += __shfl_xor(zm, o);
    }
    if (lane == 0) {
      zb += bb[0]; zg += bg[0]; zm += bgam[0];
      bgg[b * 4 + 0] = softplusf(zb);
      bgg[b * 4 + 1] = 1.f / (1.f + __expf(-zg));
      bgg[b * 4 + 2] = 1.f + softplusf(zm);
    }
  } else {
    const int NX = B_ROWS * HDIM / 4;
    const int NS = NDIM * HDIM / 4;
    const int NK = MDIM * HDIM / 4;
    const int stride = 1024 * 256;
    for (int i = (blk - 2560) * 256 + t; i < NX + NS + NK; i += stride) {
      const float* src; short* dst; int j = i;
      if (j < NX) { src = x; dst = xb; }
      else if (j < NX + NS) { j -= NX; src = Ws; dst = wsb; }
      else { j -= NX + NS; src = Wk; dst = wkb; }
      const float4 v = ((const float4*)src)[j];
      short4v o;
      o[0] = (short)f2bfu(v.x); o[1] = (short)f2bfu(v.y);
      o[2] = (short)f2bfu(v.z); o[3] = (short)f2bfu(v.w);
      ((short4v*)dst)[j] = o;
    }
  }
}

// ---------------------------------------------------------------------------
// 64x64-tile GEMM: C[m][n] = sum_k A[m][k]*W[n][k] (+bias).
// ---------------------------------------------------------------------------
template<bool AF32, bool WF32>
__global__ __launch_bounds__(256) void gemm_bt(
    const void* __restrict__ Av, const void* __restrict__ Wv,
    const float* __restrict__ bias, float* __restrict__ C,
    int ncols, int K)
{
  __shared__ __align__(16) short sA[64][40];
  __shared__ __align__(16) short sW[64][40];

  const int tid = threadIdx.x;
  const int bm = blockIdx.y, bn = blockIdx.x;
  const int lrow = tid >> 2;
  const int lcol = (tid & 3) << 3;
  const int wid = tid >> 6, lane = tid & 63;
  const int wr = wid >> 1, wc = wid & 1;
  const int fr = lane & 15, kg = (lane >> 4) << 3;

  f32x4 acc[2][2] = {};

  const size_t arow = (size_t)(bm * 64 + lrow) * K + lcol;
  const size_t wrow = (size_t)(bn * 64 + lrow) * K + lcol;

  for (int k0 = 0; k0 < K; k0 += 32) {
    if constexpr (AF32) {
      const float* A = (const float*)Av;
      const float4 a0 = *(const float4*)(A + arow + k0);
      const float4 a1 = *(const float4*)(A + arow + k0 + 4);
      *(short8*)(&sA[lrow][lcol]) = pack8(a0, a1);
    } else {
      const short* A = (const short*)Av;
      *(short8*)(&sA[lrow][lcol]) = *(const short8*)(A + arow + k0);
    }
    if constexpr (WF32) {
      const float* W = (const float*)Wv;
      const float4 w0 = *(const float4*)(W + wrow + k0);
      const float4 w1 = *(const float4*)(W + wrow + k0 + 4);
      *(short8*)(&sW[lrow][lcol]) = pack8(w0, w1);
    } else {
      const short* W = (const short*)Wv;
      *(short8*)(&sW[lrow][lcol]) = *(const short8*)(W + wrow + k0);
    }
    __syncthreads();

    short8 af[2], bf[2];
#pragma unroll
    for (int i = 0; i < 2; i++) af[i] = *(const short8*)(&sA[wr * 32 + i * 16 + fr][kg]);
#pragma unroll
    for (int n = 0; n < 2; n++) bf[n] = *(const short8*)(&sW[wc * 32 + n * 16 + fr][kg]);

#pragma unroll
    for (int i = 0; i < 2; i++)
#pragma unroll
      for (int n = 0; n < 2; n++)
        acc[i][n] = __builtin_amdgcn_mfma_f32_16x16x32_bf16(af[i], bf[n], acc[i][n], 0, 0, 0);
    __syncthreads();
  }

#pragma unroll
  for (int i = 0; i < 2; i++)
#pragma unroll
    for (int n = 0; n < 2; n++) {
      const int gr = bm * 64 + wr * 32 + i * 16 + ((lane >> 4) << 2);
      const int gc = bn * 64 + wc * 32 + n * 16 + fr;
      const float bv = bias ? bias[gc] : 0.f;
#pragma unroll
      for (int r = 0; r < 4; r++)
        C[(size_t)(gr + r) * ncols + gc] = acc[i][n][r] + bv;
    }
}

// ---------------------------------------------------------------------------
// 128x128-tile GEMM, bf16 inputs via global_load_lds width-16, linear LDS.
// ---------------------------------------------------------------------------
template<bool AF32, bool WF32>
__global__ __launch_bounds__(256) void kgemm128(
    const void* __restrict__ Av, const void* __restrict__ Wv,
    const float* __restrict__ bias, float* __restrict__ C,
    int ncols, int K)
{
  __shared__ __align__(16) short sA[128 * 32];
  __shared__ __align__(16) short sB[128 * 32];

  const int tid = threadIdx.x, lane = tid & 63, wid = tid >> 6;
  const int bm = blockIdx.y, bn = blockIdx.x;
  const int wr = wid >> 1, wc = wid & 1;
  const int fr = lane & 15, kg = (lane >> 4) << 3;

  f32x4 acc[4][4] = {};

  for (int k0 = 0; k0 < K; k0 += 32) {
    if (k0) __syncthreads();

    if constexpr (AF32) {
      const float* A = (const float*)Av;
      const int row = tid >> 1, c0 = (tid & 1) * 16;
      const float* src = A + (size_t)(bm * 128 + row) * K + k0 + c0;
      const float4 v0 = *(const float4*)src;
      const float4 v1 = *(const float4*)(src + 4);
      const float4 v2 = *(const float4*)(src + 8);
      const float4 v3 = *(const float4*)(src + 12);
      short* d = &sA[row * 32 + c0];
      *(short8*)d = pack8(v0, v1);
      *(short8*)(d + 8) = pack8(v2, v3);
    } else {
      const short* A = (const short*)Av;
#pragma unroll
      for (int j = 0; j < 2; j++) {
        const int c = tid + j * 256;
        const short* g = A + (size_t)(bm * 128 + (c >> 2)) * K + k0 + (c & 3) * 8;
        short* l = &sA[(j * 256 + wid * 64) * 8];
        __builtin_amdgcn_global_load_lds(
            (const __attribute__((address_space(1))) void*)g,
            (__attribute__((address_space(3))) void*)l, 16, 0, 0);
      }
    }

    if constexpr (WF32) {
      const float* W = (const float*)Wv;
      const int row = tid >> 1, c0 = (tid & 1) * 16;
      const float* src = W + (size_t)(bn * 128 + row) * K + k0 + c0;
      const float4 v0 = *(const float4*)src;
      const float4 v1 = *(const float4*)(src + 4);
      const float4 v2 = *(const float4*)(src + 8);
      const float4 v3 = *(const float4*)(src + 12);
      short* d = &sB[row * 32 + c0];
      *(short8*)d = pack8(v0, v1);
      *(short8*)(d + 8) = pack8(v2, v3);
    } else {
      const short* W = (const short*)Wv;
#pragma unroll
      for (int j = 0; j < 2; j++) {
        const int c = tid + j * 256;
        const short* g = W + (size_t)(bn * 128 + (c >> 2)) * K + k0 + (c & 3) * 8;
        short* l = &sB[(j * 256 + wid * 64) * 8];
        __builtin_amdgcn_global_load_lds(
            (const __attribute__((address_space(1))) void*)g,
            (__attribute__((address_space(3))) void*)l, 16, 0, 0);
      }
    }
    __syncthreads();

    short8 af[4], bf[4];
#pragma unroll
    for (int m = 0; m < 4; m++)
      af[m] = *(const short8*)(&sA[(wr * 64 + m * 16 + fr) * 32 + kg]);
#pragma unroll
    for (int n = 0; n < 4; n++)
      bf[n] = *(const short8*)(&sB[(wc * 64 + n * 16 + fr) * 32 + kg]);

#pragma unroll
    for (int m = 0; m < 4; m++)
#pragma unroll
      for (int n = 0; n < 4; n++)
        acc[m][n] = __builtin_amdgcn_mfma_f32_16x16x32_bf16(af[m], bf[n], acc[m][n], 0, 0, 0);
  }

#pragma unroll
  for (int m = 0; m < 4; m++)
#pragma unroll
    for (int n = 0; n < 4; n++) {
      const int gr = bm * 128 + wr * 64 + m * 16 + ((lane >> 4) << 2);
      const int gc = bn * 128 + wc * 64 + n * 16 + fr;
      const float bv = bias ? bias[gc] : 0.f;
#pragma unroll
      for (int r = 0; r < 4; r++)
        C[(size_t)(gr + r) * ncols + gc] = acc[m][n][r] + bv;
    }
}

// ---------------------------------------------------------------------------
// Normalize k rows: kraw (fp32) -> khat (bf16).
// ---------------------------------------------------------------------------
__global__ __launch_bounds__(128) void knorm(const float* __restrict__ kraw,
                                             short* __restrict__ khat)
{
  const int b = blockIdx.x, t = threadIdx.x;
  const int lane = t & 63, wid = t >> 6;
  const float v = kraw[(size_t)b * MDIM + t];
  float ss = v * v;
#pragma unroll
  for (int o = 32; o; o >>= 1) ss += __shfl_xor(ss, o);
  __shared__ float sred[2];
  if (lane == 0) sred[wid] = ss;
  __syncthreads();
  const float inv = 1.f / fmaxf(sqrtf(sred[0] + sred[1]), 1e-8f);
  khat[(size_t)b * MDIM + t] = (short)f2bfu(v * inv);
}

// ---------------------------------------------------------------------------
// Middle FFT stage (radix-4 Stockham DIF), computed twiddles, padded LDS.
// Reads are always at positions tid+256j; writes at q+4sp+js.
// ---------------------------------------------------------------------------
#define ANG0 (-0.0061359231515425650f)   /* -2*pi/1024 */

template<int ST>
__device__ __forceinline__ void fft_mid(const float* __restrict__ sr,
                                        const float* __restrict__ si,
                                        float* __restrict__ dr,
                                        float* __restrict__ di, int tid)
{
  const int ls = 2 * ST, s = 1 << ls;
  const int p = tid >> ls, q = tid & (s - 1), tb = tid & ~(s - 1);
  const int j0 = pad(tid), j1 = pad(tid + 256), j2 = pad(tid + 512), j3 = pad(tid + 768);
  const float a0r = sr[j0], a0i = si[j0], a1r = sr[j1], a1i = si[j1];
  const float a2r = sr[j2], a2i = si[j2], a3r = sr[j3], a3i = si[j3];
  const float b0r = a0r + a2r, b0i = a0i + a2i, b1r = a1r + a3r, b1i = a1i + a3i;
  const float b2r = a0r - a2r, b2i = a0i - a2i, b3r = a1r - a3r, b3i = a1i - a3i;
  const float A0r = b0r + b1r, A0i = b0i + b1i;
  const float A1r = b2r + b3i, A1i = b2i - b3r;
  const float A2r = b0r - b1r, A2i = b0i - b1i;
  const float A3r = b2r - b3i, A3i = b2i + b3r;
  const int o = q + 4 * s * p;
  dr[pad(o)] = A0r; di[pad(o)] = A0i;
  if constexpr (ST < 4) {
    float s1, c1; __sincosf(ANG0 * (float)tb, &s1, &c1);
    const float c2 = c1 * c1 - s1 * s1, s2 = 2.f * s1 * c1;
    const float c3 = c1 * c2 - s1 * s2, s3 = s1 * c2 + c1 * s2;
    dr[pad(o + s)]     = A1r * c1 - A1i * s1; di[pad(o + s)]     = A1r * s1 + A1i * c1;
    dr[pad(o + 2 * s)] = A2r * c2 - A2i * s2; di[pad(o + 2 * s)] = A2r * s2 + A2i * c2;
    dr[pad(o + 3 * s)] = A3r * c3 - A3i * s3; di[pad(o + 3 * s)] = A3r * s3 + A3i * c3;
  } else {
    dr[pad(o + s)]     = A1r; di[pad(o + s)]     = A1i;
    dr[pad(o + 2 * s)] = A2r; di[pad(o + 2 * s)] = A2i;
    dr[pad(o + 3 * s)] = A3r; di[pad(o + 3 * s)] = A3i;
  }
  __syncthreads();
}

// ---------------------------------------------------------------------------
// Row pass: softmaxes, gate, FFT circular conv (fused end stages), sharpen,
// normalize.  One 256-thread block per batch row.
// ---------------------------------------------------------------------------
__global__ __launch_bounds__(256) void rowpass(
    const float* __restrict__ slog, const float* __restrict__ cosb,
    const float* __restrict__ bgg, const float* __restrict__ prev,
    float* __restrict__ wout)
{
  __shared__ float bAr[1088], bAi[1088], bBr[1088], bBi[1088];
  __shared__ float sred[8];
  const int b = blockIdx.x, tid = threadIdx.x;
  const int lane = tid & 63, wid = tid >> 6;

  const float beta = bgg[b * 4 + 0], g = bgg[b * 4 + 1], gamma = bgg[b * 4 + 2];

  float sv[4], cv[4];
  float e1 = 0.f, e2 = 0.f;
#pragma unroll
  for (int i = 0; i < 4; i++) {
    sv[i] = __expf(slog[(size_t)b * NDIM + tid + i * 256]);
    cv[i] = __expf(beta * cosb[(size_t)b * NDIM + tid + i * 256]);
    e1 += sv[i]; e2 += cv[i];
  }
#pragma unroll
  for (int o = 32; o; o >>= 1) { e1 += __shfl_xor(e1, o); e2 += __shfl_xor(e2, o); }
  if (lane == 0) { sred[wid * 2] = e1; sred[wid * 2 + 1] = e2; }
  __syncthreads();
  const float r1 = 1.f / (sred[0] + sred[2] + sred[4] + sred[6]);
  const float r2 = 1.f / (sred[1] + sred[3] + sred[5] + sred[7]);

  // stage-0/0' twiddles (tb = tid), kept in registers for both FFTs
  float s1, c1; __sincosf(ANG0 * (float)tid, &s1, &c1);
  const float c2 = c1 * c1 - s1 * s1, s2 = 2.f * s1 * c1;
  const float c3 = c1 * c2 - s1 * s2, s3 = s1 * c2 + c1 * s2;

  // ---- pack + stage 0 of FFT1 in registers -> B ----
  {
    float ar[4], ai[4];
#pragma unroll
    for (int i = 0; i < 4; i++) {
      const int idx = tid + i * 256;
      const float pv = prev[(size_t)b * NDIM + idx];
      ar[i] = g * cv[i] * r2 + (1.f - g) * pv;   // w_g
      ai[i] = sv[i] * r1;                        // s
    }
    const float b0r = ar[0] + ar[2], b0i = ai[0] + ai[2];
    const float b1r = ar[1] + ar[3], b1i = ai[1] + ai[3];
    const float b2r = ar[0] - ar[2], b2i = ai[0] - ai[2];
    const float b3r = ar[1] - ar[3], b3i = ai[1] - ai[3];
    const float A0r = b0r + b1r, A0i = b0i + b1i;
    const float A1r = b2r + b3i, A1i = b2i - b3r;
    const float A2r = b0r - b1r, A2i = b0i - b1i;
    const float A3r = b2r - b3i, A3i = b2i + b3r;
    const int o4 = 4 * tid;
    bBr[pad(o4)]     = A0r;                  bBi[pad(o4)]     = A0i;
    bBr[pad(o4 + 1)] = A1r * c1 - A1i * s1;  bBi[pad(o4 + 1)] = A1r * s1 + A1i * c1;
    bBr[pad(o4 + 2)] = A2r * c2 - A2i * s2;  bBi[pad(o4 + 2)] = A2r * s2 + A2i * c2;
    bBr[pad(o4 + 3)] = A3r * c3 - A3i * s3;  bBi[pad(o4 + 3)] = A3r * s3 + A3i * c3;
  }
  __syncthreads();

  fft_mid<1>(bBr, bBi, bAr, bAi, tid);
  fft_mid<2>(bAr, bAi, bBr, bBi, tid);
  fft_mid<3>(bBr, bBi, bAr, bAi, tid);
  fft_mid<4>(bAr, bAi, bBr, bBi, tid);      // Z in B (natural order)

  // ---- split + stage 0 of FFT2 in registers -> A ----
  {
    float pr[4], pi[4];
#pragma unroll
    for (int i = 0; i < 4; i++) {
      const int k = tid + i * 256;
      const int kp = pad(k), rp = pad((1024 - k) & 1023);
      const float Zkr = bBr[kp], Zki = bBi[kp];
      const float Zrr = bBr[rp], Zri = bBi[rp];
      const float Wr = 0.5f * (Zkr + Zrr), Wi = 0.5f * (Zki - Zri);
      const float Sr = 0.5f * (Zki + Zri), Si = 0.5f * (Zrr - Zkr);
      pr[i] = Wr * Sr - Wi * Si;
      pi[i] = -(Wr * Si + Wi * Sr);
    }
    const float b0r = pr[0] + pr[2], b0i = pi[0] + pi[2];
    const float b1r = pr[1] + pr[3], b1i = pi[1] + pi[3];
    const float b2r = pr[0] - pr[2], b2i = pi[0] - pi[2];
    const float b3r = pr[1] - pr[3], b3i = pi[1] - pi[3];
    const float A0r = b0r + b1r, A0i = b0i + b1i;
    const float A1r = b2r + b3i, A1i = b2i - b3r;
    const float A2r = b0r - b1r, A2i = b0i - b1i;
    const float A3r = b2r - b3i, A3i = b2i + b3r;
    const int o4 = 4 * tid;
    bAr[pad(o4)]     = A0r;                  bAi[pad(o4)]     = A0i;
    bAr[pad(o4 + 1)] = A1r * c1 - A1i * s1;  bAi[pad(o4 + 1)] = A1r * s1 + A1i * c1;
    bAr[pad(o4 + 2)] = A2r * c2 - A2i * s2;  bAi[pad(o4 + 2)] = A2r * s2 + A2i * c2;
    bAr[pad(o4 + 3)] = A3r * c3 - A3i * s3;  bAi[pad(o4 + 3)] = A3r * s3 + A3i * c3;
  }
  __syncthreads();

  fft_mid<1>(bAr, bAi, bBr, bBi, tid);
  fft_mid<2>(bBr, bBi, bAr, bAi, tid);
  fft_mid<3>(bAr, bAi, bBr, bBi, tid);

  // ---- stage 4 of FFT2 fused with sharpen (real parts only, no stores) ----
  const int j0 = pad(tid), j1 = pad(tid + 256), j2 = pad(tid + 512), j3 = pad(tid + 768);
  const float a0r = bBr[j0], a1r = bBr[j1], a2r = bBr[j2], a3r = bBr[j3];
  const float a1i = bBi[j1], a3i = bBi[j3];
  const float b0r = a0r + a2r, b1r = a1r + a3r;
  const float b2r = a0r - a2r, b3i = a1i - a3i;
  float outr[4];
  outr[0] = b0r + b1r;   // position tid
  outr[1] = b2r + b3i;   // position tid+256
  outr[2] = b0r - b1r;   // position tid+512
  outr[3] = b2r - b3i;   // position tid+768

  float wt[4]; float esum = 0.f;
#pragma unroll
  for (int i = 0; i < 4; i++) {
    float v = outr[i] * (1.f / 1024.f);
    v = fmaxf(v, 0.f);
    const float p = (v > 0.f) ? __expf(gamma * __logf(v)) : 0.f;
    wt[i] = p; esum += p;
  }
#pragma unroll
  for (int o = 32; o; o >>= 1) esum += __shfl_xor(esum, o);
  if (lane == 0) sred[wid] = esum;
  __syncthreads();
  const float rn = 1.f / (sred[0] + sred[1] + sred[2] + sred[3] + 1e-16f);
#pragma unroll
  for (int i = 0; i < 4; i++)
    wout[(size_t)b * NDIM + tid + i * 256] = wt[i] * rn;
}

// ---------------------------------------------------------------------------
extern "C" void kernel_launch(void* const* d_in, const int* in_sizes, int n_in,
                              void* d_out, int out_size, void* d_ws, size_t ws_size,
                              hipStream_t stream)
{
  const float* x    = (const float*)d_in[0];
  const float* prev = (const float*)d_in[1];
  const float* mem  = (const float*)d_in[2];
  const float* Wk   = (const float*)d_in[3];
  const float* bk   = (const float*)d_in[4];
  const float* Wb   = (const float*)d_in[5];
  const float* bb   = (const float*)d_in[6];
  const float* Wg   = (const float*)d_in[7];
  const float* bg   = (const float*)d_in[8];
  const float* Ws   = (const float*)d_in[9];
  const float* bs   = (const float*)d_in[10];
  const float* Wgam = (const float*)d_in[11];
  const float* bgam = (const float*)d_in[12];

  // Lifetime-aliased workspace: xb/wsb/wkb/kraw die before cosb is written.
  char* ws = (char*)d_ws;
  short* mn_bf   = (short*)(ws + 0);          //  256 KB
  short* memT_bf = (short*)(ws + 262144);     //  256 KB
  short* khat    = (short*)(ws + 524288);     //    2 MB
  float* bgg     = (float*)(ws + 2621440);    //  128 KB
  float* slog    = (float*)(ws + 2752512);    //   32 MB
  float* cosb    = (float*)(ws + 36306944);   //   32 MB
  short* xb      = (short*)(ws + 36306944);   //    8 MB  } alias inside cosb
  short* wsb     = (short*)(ws + 44695552);   //    1 MB  }
  short* wkb     = (short*)(ws + 45744128);   //  128 KB  }
  float* kraw    = (float*)(ws + 45875200);   //    4 MB  }

  float* readout = (float*)d_out;                  // [8192][128]
  float* wout = readout + (size_t)B_ROWS * MDIM;   // [8192][1024]

  prep_all<<<3584, 256, 0, stream>>>(x, Ws, Wk, mem, Wb, bb, Wg, bg, Wgam, bgam,
                                     xb, wsb, wkb, mn_bf, memT_bf, bgg);
  gemm_bt<false, false><<<dim3(MDIM / 64, B_ROWS / 64), 256, 0, stream>>>(
      xb, wkb, bk, kraw, MDIM, HDIM);
  kgemm128<false, false><<<dim3(NDIM / 128, B_ROWS / 128), 256, 0, stream>>>(
      xb, wsb, bs, slog, NDIM, HDIM);
  knorm<<<B_ROWS, MDIM, 0, stream>>>(kraw, khat);
  kgemm128<false, false><<<dim3(NDIM / 128, B_ROWS / 128), 256, 0, stream>>>(
      khat, mn_bf, nullptr, cosb, NDIM, MDIM);
  rowpass<<<B_ROWS, 256, 0, stream>>>(slog, cosb, bgg, prev, wout);
  gemm_bt<true, false><<<dim3(MDIM / 64, B_ROWS / 64), 256, 0, stream>>>(
      wout, memT_bf, nullptr, readout, MDIM, NDIM);
}

// Round 7
// 126.380 us; speedup vs baseline: 1.3866x; 1.0168x over previous
//
#include <hip/hip_runtime.h>
#include <hip/hip_bf16.h>

typedef __attribute__((ext_vector_type(8))) short short8;
typedef __attribute__((ext_vector_type(4))) short short4v;
typedef __attribute__((ext_vector_type(4))) float f32x4;

#define B_ROWS 8192
#define HDIM 512
#define NDIM 1024
#define MDIM 128

__device__ __forceinline__ float softplusf(float z) {
  return fmaxf(z, 0.f) + log1pf(__expf(-fabsf(z)));
}
__device__ __forceinline__ unsigned short f2bfu(float f) {
  __hip_bfloat16 h = __float2bfloat16(f);   // round-to-nearest-even
  return *reinterpret_cast<unsigned short*>(&h);
}
__device__ __forceinline__ short8 pack8(float4 a, float4 b) {
  short8 r;
  r[0] = (short)f2bfu(a.x); r[1] = (short)f2bfu(a.y);
  r[2] = (short)f2bfu(a.z); r[3] = (short)f2bfu(a.w);
  r[4] = (short)f2bfu(b.x); r[5] = (short)f2bfu(b.y);
  r[6] = (short)f2bfu(b.z); r[7] = (short)f2bfu(b.w);
  return r;
}
__device__ __forceinline__ int pad(int i) { return i + (i >> 4); }

// ---------------------------------------------------------------------------
// Merged prologue: prep_mem (blocks 0..511), scalars (512..2559),
// fp32->bf16 prepack of x/Ws/Wk (2560..3583, grid-stride).
// ---------------------------------------------------------------------------
__global__ __launch_bounds__(256) void prep_all(
    const float* __restrict__ x, const float* __restrict__ Ws,
    const float* __restrict__ Wk, const float* __restrict__ mem,
    const float* __restrict__ Wb, const float* __restrict__ bb,
    const float* __restrict__ Wg, const float* __restrict__ bg,
    const float* __restrict__ Wgam, const float* __restrict__ bgam,
    short* __restrict__ xb, short* __restrict__ wsb, short* __restrict__ wkb,
    short* __restrict__ mn_bf, short* __restrict__ memT_bf,
    float* __restrict__ bgg)
{
  const int blk = blockIdx.x, t = threadIdx.x;
  if (blk < 512) {
    __shared__ float sredp[4];
    const int half = t >> 7, tl = t & 127;
    const int n = blk * 2 + half;
    const int wid = t >> 6;
    const float v = mem[n * MDIM + tl];
    float ss = v * v;
#pragma unroll
    for (int o = 32; o; o >>= 1) ss += __shfl_xor(ss, o);
    if ((t & 63) == 0) sredp[wid] = ss;
    __syncthreads();
    const float inv = 1.f / fmaxf(sqrtf(sredp[half * 2] + sredp[half * 2 + 1]), 1e-8f);
    mn_bf[n * MDIM + tl] = (short)f2bfu(v * inv);
    memT_bf[(size_t)tl * NDIM + n] = (short)f2bfu(v);
  } else if (blk < 2560) {
    const int wid = t >> 6, lane = t & 63;
    const int b = (blk - 512) * 4 + wid;
    const size_t xo = (size_t)b * HDIM + lane * 8;
    const float4 x0 = *(const float4*)(x + xo);
    const float4 x1 = *(const float4*)(x + xo + 4);
    const float4 b0 = *(const float4*)(Wb + lane * 8);
    const float4 b1 = *(const float4*)(Wb + lane * 8 + 4);
    const float4 g0 = *(const float4*)(Wg + lane * 8);
    const float4 g1 = *(const float4*)(Wg + lane * 8 + 4);
    const float4 m0 = *(const float4*)(Wgam + lane * 8);
    const float4 m1 = *(const float4*)(Wgam + lane * 8 + 4);
    float zb = x0.x*b0.x + x0.y*b0.y + x0.z*b0.z + x0.w*b0.w
             + x1.x*b1.x + x1.y*b1.y + x1.z*b1.z + x1.w*b1.w;
    float zg = x0.x*g0.x + x0.y*g0.y + x0.z*g0.z + x0.w*g0.w
             + x1.x*g1.x + x1.y*g1.y + x1.z*g1.z + x1.w*g1.w;
    float zm = x0.x*m0.x + x0.y*m0.y + x0.z*m0.z + x0.w*m0.w
             + x1.x*m1.x + x1.y*m1.y + x1.z*m1.z + x1.w*m1.w;
#pragma unroll
    for (int o = 32; o; o >>= 1) {
      zb += __shfl_xor(zb, o); zg += __shfl_xor(zg, o); zm += __shfl_xor(zm, o);
    }
    if (lane == 0) {
      zb += bb[0]; zg += bg[0]; zm += bgam[0];
      bgg[b * 4 + 0] = softplusf(zb);
      bgg[b * 4 + 1] = 1.f / (1.f + __expf(-zg));
      bgg[b * 4 + 2] = 1.f + softplusf(zm);
    }
  } else {
    const int NX = B_ROWS * HDIM / 4;
    const int NS = NDIM * HDIM / 4;
    const int NK = MDIM * HDIM / 4;
    const int stride = 1024 * 256;
    for (int i = (blk - 2560) * 256 + t; i < NX + NS + NK; i += stride) {
      const float* src; short* dst; int j = i;
      if (j < NX) { src = x; dst = xb; }
      else if (j < NX + NS) { j -= NX; src = Ws; dst = wsb; }
      else { j -= NX + NS; src = Wk; dst = wkb; }
      const float4 v = ((const float4*)src)[j];
      short4v o;
      o[0] = (short)f2bfu(v.x); o[1] = (short)f2bfu(v.y);
      o[2] = (short)f2bfu(v.z); o[3] = (short)f2bfu(v.w);
      ((short4v*)dst)[j] = o;
    }
  }
}

// ---------------------------------------------------------------------------
// k-GEMM with fused row-norm epilogue: khat = (x Wk^T + bk) / ||.||, bf16.
// 32 rows x 128 cols per block, 4 waves (1x4 cols), K=512. Grid 256.
// ---------------------------------------------------------------------------
__global__ __launch_bounds__(256) void kgemm_norm(
    const short* __restrict__ xb, const short* __restrict__ wkb,
    const float* __restrict__ bk, short* __restrict__ khat)
{
  __shared__ __align__(16) short sA[32][40];
  __shared__ __align__(16) short sW[128][40];
  __shared__ float snorm[4][32];
  __shared__ float sinv[32];

  const int tid = threadIdx.x, lane = tid & 63, wid = tid >> 6;
  const int bm = blockIdx.x;
  const int fr = lane & 15, kg = (lane >> 4) << 3;

  f32x4 acc[2][2] = {};

  for (int k0 = 0; k0 < HDIM; k0 += 32) {
    if (k0) __syncthreads();
    if (tid < 128) {
      const int row = tid >> 2, c0 = (tid & 3) * 8;
      *(short8*)(&sA[row][c0]) =
          *(const short8*)(xb + (size_t)(bm * 32 + row) * HDIM + k0 + c0);
    }
#pragma unroll
    for (int u = tid; u < 512; u += 256) {
      const int row = u >> 2, c0 = (u & 3) * 8;
      *(short8*)(&sW[row][c0]) =
          *(const short8*)(wkb + (size_t)row * HDIM + k0 + c0);
    }
    __syncthreads();

    short8 af[2], bf[2];
#pragma unroll
    for (int i = 0; i < 2; i++) af[i] = *(const short8*)(&sA[i * 16 + fr][kg]);
#pragma unroll
    for (int n = 0; n < 2; n++) bf[n] = *(const short8*)(&sW[wid * 32 + n * 16 + fr][kg]);
#pragma unroll
    for (int i = 0; i < 2; i++)
#pragma unroll
      for (int n = 0; n < 2; n++)
        acc[i][n] = __builtin_amdgcn_mfma_f32_16x16x32_bf16(af[i], bf[n], acc[i][n], 0, 0, 0);
  }

  // epilogue: bias, row-norm, write khat bf16
  const int rbase = (lane >> 4) << 2;
  float z[2][2][4];
#pragma unroll
  for (int i = 0; i < 2; i++)
#pragma unroll
    for (int n = 0; n < 2; n++) {
      const float bv = bk[wid * 32 + n * 16 + fr];
#pragma unroll
      for (int r = 0; r < 4; r++) z[i][n][r] = acc[i][n][r] + bv;
    }
#pragma unroll
  for (int i = 0; i < 2; i++)
#pragma unroll
    for (int r = 0; r < 4; r++) {
      float sq = z[i][0][r] * z[i][0][r] + z[i][1][r] * z[i][1][r];
      sq += __shfl_xor(sq, 1); sq += __shfl_xor(sq, 2);
      sq += __shfl_xor(sq, 4); sq += __shfl_xor(sq, 8);
      if (fr == 0) snorm[wid][i * 16 + rbase + r] = sq;
    }
  __syncthreads();
  if (tid < 32) {
    const float nn = snorm[0][tid] + snorm[1][tid] + snorm[2][tid] + snorm[3][tid];
    sinv[tid] = 1.f / fmaxf(sqrtf(nn), 1e-8f);
  }
  __syncthreads();
#pragma unroll
  for (int i = 0; i < 2; i++)
#pragma unroll
    for (int n = 0; n < 2; n++)
#pragma unroll
      for (int r = 0; r < 4; r++) {
        const int grl = i * 16 + rbase + r;
        khat[(size_t)(bm * 32 + grl) * MDIM + wid * 32 + n * 16 + fr] =
            (short)f2bfu(z[i][n][r] * sinv[grl]);
      }
}

// ---------------------------------------------------------------------------
// 64x64-tile GEMM: C[m][n] = sum_k A[m][k]*W[n][k] (+bias).
// ---------------------------------------------------------------------------
template<bool AF32, bool WF32>
__global__ __launch_bounds__(256) void gemm_bt(
    const void* __restrict__ Av, const void* __restrict__ Wv,
    const float* __restrict__ bias, float* __restrict__ C,
    int ncols, int K)
{
  __shared__ __align__(16) short sA[64][40];
  __shared__ __align__(16) short sW[64][40];

  const int tid = threadIdx.x;
  const int bm = blockIdx.y, bn = blockIdx.x;
  const int lrow = tid >> 2;
  const int lcol = (tid & 3) << 3;
  const int wid = tid >> 6, lane = tid & 63;
  const int wr = wid >> 1, wc = wid & 1;
  const int fr = lane & 15, kg = (lane >> 4) << 3;

  f32x4 acc[2][2] = {};

  const size_t arow = (size_t)(bm * 64 + lrow) * K + lcol;
  const size_t wrow = (size_t)(bn * 64 + lrow) * K + lcol;

  for (int k0 = 0; k0 < K; k0 += 32) {
    if constexpr (AF32) {
      const float* A = (const float*)Av;
      const float4 a0 = *(const float4*)(A + arow + k0);
      const float4 a1 = *(const float4*)(A + arow + k0 + 4);
      *(short8*)(&sA[lrow][lcol]) = pack8(a0, a1);
    } else {
      const short* A = (const short*)Av;
      *(short8*)(&sA[lrow][lcol]) = *(const short8*)(A + arow + k0);
    }
    if constexpr (WF32) {
      const float* W = (const float*)Wv;
      const float4 w0 = *(const float4*)(W + wrow + k0);
      const float4 w1 = *(const float4*)(W + wrow + k0 + 4);
      *(short8*)(&sW[lrow][lcol]) = pack8(w0, w1);
    } else {
      const short* W = (const short*)Wv;
      *(short8*)(&sW[lrow][lcol]) = *(const short8*)(W + wrow + k0);
    }
    __syncthreads();

    short8 af[2], bf[2];
#pragma unroll
    for (int i = 0; i < 2; i++) af[i] = *(const short8*)(&sA[wr * 32 + i * 16 + fr][kg]);
#pragma unroll
    for (int n = 0; n < 2; n++) bf[n] = *(const short8*)(&sW[wc * 32 + n * 16 + fr][kg]);

#pragma unroll
    for (int i = 0; i < 2; i++)
#pragma unroll
      for (int n = 0; n < 2; n++)
        acc[i][n] = __builtin_amdgcn_mfma_f32_16x16x32_bf16(af[i], bf[n], acc[i][n], 0, 0, 0);
    __syncthreads();
  }

#pragma unroll
  for (int i = 0; i < 2; i++)
#pragma unroll
    for (int n = 0; n < 2; n++) {
      const int gr = bm * 64 + wr * 32 + i * 16 + ((lane >> 4) << 2);
      const int gc = bn * 64 + wc * 32 + n * 16 + fr;
      const float bv = bias ? bias[gc] : 0.f;
#pragma unroll
      for (int r = 0; r < 4; r++)
        C[(size_t)(gr + r) * ncols + gc] = acc[i][n][r] + bv;
    }
}

// ---------------------------------------------------------------------------
// 128x128-tile GEMM, bf16 inputs via global_load_lds width-16, linear LDS.
// ---------------------------------------------------------------------------
template<bool AF32, bool WF32>
__global__ __launch_bounds__(256) void kgemm128(
    const void* __restrict__ Av, const void* __restrict__ Wv,
    const float* __restrict__ bias, float* __restrict__ C,
    int ncols, int K)
{
  __shared__ __align__(16) short sA[128 * 32];
  __shared__ __align__(16) short sB[128 * 32];

  const int tid = threadIdx.x, lane = tid & 63, wid = tid >> 6;
  const int bm = blockIdx.y, bn = blockIdx.x;
  const int wr = wid >> 1, wc = wid & 1;
  const int fr = lane & 15, kg = (lane >> 4) << 3;

  f32x4 acc[4][4] = {};

  for (int k0 = 0; k0 < K; k0 += 32) {
    if (k0) __syncthreads();

    if constexpr (AF32) {
      const float* A = (const float*)Av;
      const int row = tid >> 1, c0 = (tid & 1) * 16;
      const float* src = A + (size_t)(bm * 128 + row) * K + k0 + c0;
      const float4 v0 = *(const float4*)src;
      const float4 v1 = *(const float4*)(src + 4);
      const float4 v2 = *(const float4*)(src + 8);
      const float4 v3 = *(const float4*)(src + 12);
      short* d = &sA[row * 32 + c0];
      *(short8*)d = pack8(v0, v1);
      *(short8*)(d + 8) = pack8(v2, v3);
    } else {
      const short* A = (const short*)Av;
#pragma unroll
      for (int j = 0; j < 2; j++) {
        const int c = tid + j * 256;
        const short* g = A + (size_t)(bm * 128 + (c >> 2)) * K + k0 + (c & 3) * 8;
        short* l = &sA[(j * 256 + wid * 64) * 8];
        __builtin_amdgcn_global_load_lds(
            (const __attribute__((address_space(1))) void*)g,
            (__attribute__((address_space(3))) void*)l, 16, 0, 0);
      }
    }

    if constexpr (WF32) {
      const float* W = (const float*)Wv;
      const int row = tid >> 1, c0 = (tid & 1) * 16;
      const float* src = W + (size_t)(bn * 128 + row) * K + k0 + c0;
      const float4 v0 = *(const float4*)src;
      const float4 v1 = *(const float4*)(src + 4);
      const float4 v2 = *(const float4*)(src + 8);
      const float4 v3 = *(const float4*)(src + 12);
      short* d = &sB[row * 32 + c0];
      *(short8*)d = pack8(v0, v1);
      *(short8*)(d + 8) = pack8(v2, v3);
    } else {
      const short* W = (const short*)Wv;
#pragma unroll
      for (int j = 0; j < 2; j++) {
        const int c = tid + j * 256;
        const short* g = W + (size_t)(bn * 128 + (c >> 2)) * K + k0 + (c & 3) * 8;
        short* l = &sB[(j * 256 + wid * 64) * 8];
        __builtin_amdgcn_global_load_lds(
            (const __attribute__((address_space(1))) void*)g,
            (__attribute__((address_space(3))) void*)l, 16, 0, 0);
      }
    }
    __syncthreads();

    short8 af[4], bf[4];
#pragma unroll
    for (int m = 0; m < 4; m++)
      af[m] = *(const short8*)(&sA[(wr * 64 + m * 16 + fr) * 32 + kg]);
#pragma unroll
    for (int n = 0; n < 4; n++)
      bf[n] = *(const short8*)(&sB[(wc * 64 + n * 16 + fr) * 32 + kg]);

#pragma unroll
    for (int m = 0; m < 4; m++)
#pragma unroll
      for (int n = 0; n < 4; n++)
        acc[m][n] = __builtin_amdgcn_mfma_f32_16x16x32_bf16(af[m], bf[n], acc[m][n], 0, 0, 0);
  }

#pragma unroll
  for (int m = 0; m < 4; m++)
#pragma unroll
    for (int n = 0; n < 4; n++) {
      const int gr = bm * 128 + wr * 64 + m * 16 + ((lane >> 4) << 2);
      const int gc = bn * 128 + wc * 64 + n * 16 + fr;
      const float bv = bias ? bias[gc] : 0.f;
#pragma unroll
      for (int r = 0; r < 4; r++)
        C[(size_t)(gr + r) * ncols + gc] = acc[m][n][r] + bv;
    }
}

// ---------------------------------------------------------------------------
// FFT pieces. ANG0 = -2*pi/1024.
// ---------------------------------------------------------------------------
#define ANG0 (-0.0061359231515425650f)

template<int ST>
__device__ __forceinline__ void fft_mid(const float* __restrict__ sr,
                                        const float* __restrict__ si,
                                        float* __restrict__ dr,
                                        float* __restrict__ di, int tid,
                                        int j0, int j1, int j2, int j3)
{
  const int ls = 2 * ST, s = 1 << ls;
  const int p = tid >> ls, q = tid & (s - 1), tb = tid & ~(s - 1);
  const float a0r = sr[j0], a0i = si[j0], a1r = sr[j1], a1i = si[j1];
  const float a2r = sr[j2], a2i = si[j2], a3r = sr[j3], a3i = si[j3];
  const float b0r = a0r + a2r, b0i = a0i + a2i, b1r = a1r + a3r, b1i = a1i + a3i;
  const float b2r = a0r - a2r, b2i = a0i - a2i, b3r = a1r - a3r, b3i = a1i - a3i;
  const float A0r = b0r + b1r, A0i = b0i + b1i;
  const float A1r = b2r + b3i, A1i = b2i - b3r;
  const float A2r = b0r - b1r, A2i = b0i - b1i;
  const float A3r = b2r - b3i, A3i = b2i + b3r;
  const int o = q + 4 * s * p;
  dr[pad(o)] = A0r; di[pad(o)] = A0i;
  if constexpr (ST < 4) {
    float s1, c1; __sincosf(ANG0 * (float)tb, &s1, &c1);
    const float c2 = c1 * c1 - s1 * s1, s2 = 2.f * s1 * c1;
    const float c3 = c1 * c2 - s1 * s2, s3 = s1 * c2 + c1 * s2;
    dr[pad(o + s)]     = A1r * c1 - A1i * s1; di[pad(o + s)]     = A1r * s1 + A1i * c1;
    dr[pad(o + 2 * s)] = A2r * c2 - A2i * s2; di[pad(o + 2 * s)] = A2r * s2 + A2i * c2;
    dr[pad(o + 3 * s)] = A3r * c3 - A3i * s3; di[pad(o + 3 * s)] = A3r * s3 + A3i * c3;
  } else {
    dr[pad(o + s)]     = A1r; di[pad(o + s)]     = A1i;
    dr[pad(o + 2 * s)] = A2r; di[pad(o + 2 * s)] = A2i;
    dr[pad(o + 3 * s)] = A3r; di[pad(o + 3 * s)] = A3i;
  }
  __syncthreads();
}

// Half-width radix-4 stage of the 512-pt FFT (threads 0..127 active).
// (s,ns): J=1 -> (2,256); J=2 -> (8,64); J=3 -> (32,16).
template<int J>
__device__ __forceinline__ void fft512_mid(const float* __restrict__ sr,
                                           const float* __restrict__ si,
                                           float* __restrict__ dr,
                                           float* __restrict__ di, int tid)
{
  if (tid < 128) {
    constexpr int s  = (J == 1) ? 2 : (J == 2) ? 8 : 32;
    constexpr int ns = (J == 1) ? 256 : (J == 2) ? 64 : 16;
    constexpr int ls = (J == 1) ? 1 : (J == 2) ? 3 : 5;
    const int p = tid >> ls, q = tid & (s - 1);
    const float a0r = sr[pad(tid)],       a0i = si[pad(tid)];
    const float a1r = sr[pad(tid + 128)], a1i = si[pad(tid + 128)];
    const float a2r = sr[pad(tid + 256)], a2i = si[pad(tid + 256)];
    const float a3r = sr[pad(tid + 384)], a3i = si[pad(tid + 384)];
    const float b0r = a0r + a2r, b0i = a0i + a2i, b1r = a1r + a3r, b1i = a1i + a3i;
    const float b2r = a0r - a2r, b2i = a0i - a2i, b3r = a1r - a3r, b3i = a1i - a3i;
    const float A0r = b0r + b1r, A0i = b0i + b1i;
    const float A1r = b2r + b3i, A1i = b2i - b3r;
    const float A2r = b0r - b1r, A2i = b0i - b1i;
    const float A3r = b2r - b3i, A3i = b2i + b3r;
    float s1, c1; __sincosf((-6.283185307179586f / (float)ns) * (float)p, &s1, &c1);
    const float c2 = c1 * c1 - s1 * s1, s2 = 2.f * s1 * c1;
    const float c3 = c1 * c2 - s1 * s2, s3 = s1 * c2 + c1 * s2;
    const int o = q + 4 * s * p;
    dr[pad(o)]         = A0r;                 di[pad(o)]         = A0i;
    dr[pad(o + s)]     = A1r * c1 - A1i * s1; di[pad(o + s)]     = A1r * s1 + A1i * c1;
    dr[pad(o + 2 * s)] = A2r * c2 - A2i * s2; di[pad(o + 2 * s)] = A2r * s2 + A2i * c2;
    dr[pad(o + 3 * s)] = A3r * c3 - A3i * s3; di[pad(o + 3 * s)] = A3r * s3 + A3i * c3;
  }
  __syncthreads();
}

// ---------------------------------------------------------------------------
// Row pass: softmaxes, gate, FFT1 (1024), Hermitian product, irfft via 512,
// sharpen, normalize.  One 256-thread block per batch row.
// ---------------------------------------------------------------------------
__global__ __launch_bounds__(256) void rowpass(
    const float* __restrict__ slog, const float* __restrict__ cosb,
    const float* __restrict__ bgg, const float* __restrict__ prev,
    float* __restrict__ wout)
{
  __shared__ float bAr[1088], bAi[1088], bBr[1088], bBi[1088];
  __shared__ float sred[8];
  const int b = blockIdx.x, tid = threadIdx.x;
  const int lane = tid & 63, wid = tid >> 6;
  const int j0 = pad(tid), j1 = pad(tid + 256), j2 = pad(tid + 512), j3 = pad(tid + 768);

  const float beta = bgg[b * 4 + 0], g = bgg[b * 4 + 1], gamma = bgg[b * 4 + 2];

  float sv[4], cv[4];
  float e1 = 0.f, e2 = 0.f;
#pragma unroll
  for (int i = 0; i < 4; i++) {
    sv[i] = __expf(slog[(size_t)b * NDIM + tid + i * 256]);
    cv[i] = __expf(beta * cosb[(size_t)b * NDIM + tid + i * 256]);
    e1 += sv[i]; e2 += cv[i];
  }
#pragma unroll
  for (int o = 32; o; o >>= 1) { e1 += __shfl_xor(e1, o); e2 += __shfl_xor(e2, o); }
  if (lane == 0) { sred[wid * 2] = e1; sred[wid * 2 + 1] = e2; }
  __syncthreads();
  const float r1 = 1.f / (sred[0] + sred[2] + sred[4] + sred[6]);
  const float r2 = 1.f / (sred[1] + sred[3] + sred[5] + sred[7]);

  // stage-0 twiddles for FFT1
  float s1, c1; __sincosf(ANG0 * (float)tid, &s1, &c1);
  const float c2 = c1 * c1 - s1 * s1, s2 = 2.f * s1 * c1;
  const float c3 = c1 * c2 - s1 * s2, s3 = s1 * c2 + c1 * s2;

  // ---- pack + stage 0 of FFT1 in registers -> B ----
  {
    float ar[4], ai[4];
#pragma unroll
    for (int i = 0; i < 4; i++) {
      const int idx = tid + i * 256;
      const float pv = prev[(size_t)b * NDIM + idx];
      ar[i] = g * cv[i] * r2 + (1.f - g) * pv;   // w_g
      ai[i] = sv[i] * r1;                        // s
    }
    const float b0r = ar[0] + ar[2], b0i = ai[0] + ai[2];
    const float b1r = ar[1] + ar[3], b1i = ai[1] + ai[3];
    const float b2r = ar[0] - ar[2], b2i = ai[0] - ai[2];
    const float b3r = ar[1] - ar[3], b3i = ai[1] - ai[3];
    const float A0r = b0r + b1r, A0i = b0i + b1i;
    const float A1r = b2r + b3i, A1i = b2i - b3r;
    const float A2r = b0r - b1r, A2i = b0i - b1i;
    const float A3r = b2r - b3i, A3i = b2i + b3r;
    const int o4 = 4 * tid;
    bBr[pad(o4)]     = A0r;                  bBi[pad(o4)]     = A0i;
    bBr[pad(o4 + 1)] = A1r * c1 - A1i * s1;  bBi[pad(o4 + 1)] = A1r * s1 + A1i * c1;
    bBr[pad(o4 + 2)] = A2r * c2 - A2i * s2;  bBi[pad(o4 + 2)] = A2r * s2 + A2i * c2;
    bBr[pad(o4 + 3)] = A3r * c3 - A3i * s3;  bBi[pad(o4 + 3)] = A3r * s3 + A3i * c3;
  }
  __syncthreads();

  fft_mid<1>(bBr, bBi, bAr, bAi, tid, j0, j1, j2, j3);
  fft_mid<2>(bAr, bAi, bBr, bBi, tid, j0, j1, j2, j3);
  fft_mid<3>(bBr, bBi, bAr, bAi, tid, j0, j1, j2, j3);
  fft_mid<4>(bAr, bAi, bBr, bBi, tid, j0, j1, j2, j3);   // Z in B, natural order

  // ---- Hermitian product: P[k] = W[k]*S[k], k = 0..512 -> A ----
#pragma unroll
  for (int i = 0; i < 2; i++) {
    const int k = tid + i * 256;
    const int kp = pad(k), rp = pad((1024 - k) & 1023);
    const float Zkr = bBr[kp], Zki = bBi[kp];
    const float Zrr = bBr[rp], Zri = bBi[rp];
    const float Wr = 0.5f * (Zkr + Zrr), Wi = 0.5f * (Zki - Zri);
    const float Sr = 0.5f * (Zki + Zri), Si = 0.5f * (Zrr - Zkr);
    bAr[kp] = Wr * Sr - Wi * Si;
    bAi[kp] = Wr * Si + Wi * Sr;
  }
  if (tid == 0) {
    const int kp = pad(512);
    bAr[kp] = bBr[kp] * bBi[kp];   // W=Re(Z512), S=Im(Z512), both real
    bAi[kp] = 0.f;
  }
  __syncthreads();

  // ---- Q construction + conj + radix-2 register stage -> B (512 pts) ----
  {
    // E[t] = e^{+i*pi*t/512}
    float es, ec; __sincosf(0.0061359231515425650f * (float)tid, &es, &ec);
    const float P0r = bAr[pad(tid)],       P0i = bAi[pad(tid)];
    const float Pa0r = bAr[pad(512 - tid)], Pa0i = bAi[pad(512 - tid)];
    const float S0r = P0r + Pa0r, S0i = P0i - Pa0i;
    const float D0r = P0r - Pa0r, D0i = P0i + Pa0i;
    const float Q0r = S0r - es * D0r - ec * D0i;
    const float Q0i = S0i + ec * D0r - es * D0i;
    const float P1r = bAr[pad(tid + 256)],  P1i = bAi[pad(tid + 256)];
    const float Pa1r = bAr[pad(256 - tid)], Pa1i = bAi[pad(256 - tid)];
    const float S1r = P1r + Pa1r, S1i = P1i - Pa1i;
    const float D1r = P1r - Pa1r, D1i = P1i + Pa1i;
    // E' = i*E  ->  i*E' = -E
    const float Q1r = S1r - ec * D1r + es * D1i;
    const float Q1i = S1i - es * D1r - ec * D1i;
    // conj(Q) then radix-2 DIF with twiddle e^{-2pi i t/512}
    const float ur = Q0r, ui = -Q0i, vr = Q1r, vi = -Q1i;
    float ts, tc; __sincosf(-0.012271846303085130f * (float)tid, &ts, &tc);
    const float d_r = ur - vr, d_i = ui - vi;
    bBr[pad(2 * tid)]     = ur + vr;             bBi[pad(2 * tid)]     = ui + vi;
    bBr[pad(2 * tid + 1)] = d_r * tc - d_i * ts; bBi[pad(2 * tid + 1)] = d_r * ts + d_i * tc;
  }
  __syncthreads();

  fft512_mid<1>(bBr, bBi, bAr, bAi, tid);
  fft512_mid<2>(bAr, bAi, bBr, bBi, tid);
  fft512_mid<3>(bBr, bBi, bAr, bAi, tid);

  // final 4-pt stage (no twiddles), y -> B
  if (tid < 128) {
    const int i0 = pad(tid), i1 = pad(tid + 128), i2 = pad(tid + 256), i3 = pad(tid + 384);
    const float a0r = bAr[i0], a0i = bAi[i0], a1r = bAr[i1], a1i = bAi[i1];
    const float a2r = bAr[i2], a2i = bAi[i2], a3r = bAr[i3], a3i = bAi[i3];
    const float b0r = a0r + a2r, b0i = a0i + a2i, b1r = a1r + a3r, b1i = a1i + a3i;
    const float b2r = a0r - a2r, b2i = a0i - a2i, b3r = a1r - a3r, b3i = a1i - a3i;
    bBr[i0] = b0r + b1r; bBi[i0] = b0i + b1i;
    bBr[i1] = b2r + b3i; bBi[i1] = b2i - b3r;
    bBr[i2] = b0r - b1r; bBi[i2] = b0i - b1i;
    bBr[i3] = b2r - b3i; bBi[i3] = b2i + b3r;
  }
  __syncthreads();

  // ---- y -> x, sharpen, normalize; x[4t..4t+3] per thread ----
  const int m0 = pad(2 * tid), m1 = pad(2 * tid + 1);
  float xv[4];
  xv[0] =  bBr[m0] * (1.f / 1024.f);
  xv[1] = -bBi[m0] * (1.f / 1024.f);
  xv[2] =  bBr[m1] * (1.f / 1024.f);
  xv[3] = -bBi[m1] * (1.f / 1024.f);

  float wt[4]; float esum = 0.f;
#pragma unroll
  for (int i = 0; i < 4; i++) {
    const float v = fmaxf(xv[i], 0.f);
    const float p = (v > 0.f) ? __expf(gamma * __logf(v)) : 0.f;
    wt[i] = p; esum += p;
  }
#pragma unroll
  for (int o = 32; o; o >>= 1) esum += __shfl_xor(esum, o);
  if (lane == 0) sred[wid] = esum;
  __syncthreads();
  const float rn = 1.f / (sred[0] + sred[1] + sred[2] + sred[3] + 1e-16f);
  *(float4*)(wout + (size_t)b * NDIM + 4 * tid) =
      make_float4(wt[0] * rn, wt[1] * rn, wt[2] * rn, wt[3] * rn);
}

// ---------------------------------------------------------------------------
extern "C" void kernel_launch(void* const* d_in, const int* in_sizes, int n_in,
                              void* d_out, int out_size, void* d_ws, size_t ws_size,
                              hipStream_t stream)
{
  const float* x    = (const float*)d_in[0];
  const float* prev = (const float*)d_in[1];
  const float* mem  = (const float*)d_in[2];
  const float* Wk   = (const float*)d_in[3];
  const float* bk   = (const float*)d_in[4];
  const float* Wb   = (const float*)d_in[5];
  const float* bb   = (const float*)d_in[6];
  const float* Wg   = (const float*)d_in[7];
  const float* bg   = (const float*)d_in[8];
  const float* Ws   = (const float*)d_in[9];
  const float* bs   = (const float*)d_in[10];
  const float* Wgam = (const float*)d_in[11];
  const float* bgam = (const float*)d_in[12];

  // Lifetime-aliased workspace: xb/wsb/wkb die before cosb is written.
  char* ws = (char*)d_ws;
  short* mn_bf   = (short*)(ws + 0);          //  256 KB
  short* memT_bf = (short*)(ws + 262144);     //  256 KB
  short* khat    = (short*)(ws + 524288);     //    2 MB
  float* bgg     = (float*)(ws + 2621440);    //  128 KB
  float* slog    = (float*)(ws + 2752512);    //   32 MB
  float* cosb    = (float*)(ws + 36306944);   //   32 MB
  short* xb      = (short*)(ws + 36306944);   //    8 MB  } alias inside cosb
  short* wsb     = (short*)(ws + 44695552);   //    1 MB  }
  short* wkb     = (short*)(ws + 45744128);   //  128 KB  }

  float* readout = (float*)d_out;                  // [8192][128]
  float* wout = readout + (size_t)B_ROWS * MDIM;   // [8192][1024]

  prep_all<<<3584, 256, 0, stream>>>(x, Ws, Wk, mem, Wb, bb, Wg, bg, Wgam, bgam,
                                     xb, wsb, wkb, mn_bf, memT_bf, bgg);
  kgemm_norm<<<B_ROWS / 32, 256, 0, stream>>>(xb, wkb, bk, khat);
  kgemm128<false, false><<<dim3(NDIM / 128, B_ROWS / 128), 256, 0, stream>>>(
      xb, wsb, bs, slog, NDIM, HDIM);
  kgemm128<false, false><<<dim3(NDIM / 128, B_ROWS / 128), 256, 0, stream>>>(
      khat, mn_bf, nullptr, cosb, NDIM, MDIM);
  rowpass<<<B_ROWS, 256, 0, stream>>>(slog, cosb, bgg, prev, wout);
  gemm_bt<true, false><<<dim3(MDIM / 64, B_ROWS / 64), 256, 0, stream>>>(
      wout, memT_bf, nullptr, readout, MDIM, NDIM);
}